// Round 2
// baseline (6500.484 us; speedup 1.0000x reference)
//
#include <hip/hip_runtime.h>

#define EPS 1e-5f

__device__ __forceinline__ float wave_sum(float v) {
  #pragma unroll
  for (int o = 32; o > 0; o >>= 1) v += __shfl_down(v, o, 64);
  return v;
}

__device__ __forceinline__ void atomic_add_f(float* p, float v) {
  unsafeAtomicAdd(p, v);  // HW global_atomic_add_f32, no CAS loop
}

// ---- degree count (before +1 self loop) ----
__global__ void __launch_bounds__(256) k_deg(const int* __restrict__ dst, int E,
                                             int* __restrict__ cnt) {
  int i = blockIdx.x * blockDim.x + threadIdx.x;
  if (i < E) atomicAdd(&cnt[dst[i]], 1);
}

// ---- bn0 stats: sum, sumsq of x ----
__global__ void __launch_bounds__(256) k_s0(const float* __restrict__ x, int N,
                                            float* __restrict__ sums) {
  float s = 0.f, q = 0.f;
  for (int i = blockIdx.x * blockDim.x + threadIdx.x; i < N; i += gridDim.x * blockDim.x) {
    float v = x[i];
    s += v;
    q = fmaf(v, v, q);
  }
  s = wave_sum(s);
  q = wave_sum(q);
  if ((threadIdx.x & 63) == 0) { atomic_add_f(&sums[0], s); atomic_add_f(&sums[1], q); }
}

// ---- bn0 affine: h0 = x*ab[0] + ab[1] ----
__global__ void __launch_bounds__(64) k_c0(const float* __restrict__ sums,
                                           const float* __restrict__ g,
                                           const float* __restrict__ b, float invN,
                                           float* __restrict__ ab) {
  float mu = sums[0] * invN;
  float var = fmaf(-mu, mu, sums[1] * invN);
  float r = rsqrtf(var + EPS);
  float a = g[0] * r;
  ab[0] = a;
  ab[1] = b[0] - mu * a;
}

// ---- dinv = rsqrt(deg+1); agg1 init with self-loop term of h0 ----
__global__ void __launch_bounds__(256) k_dinv_init(const int* __restrict__ cnt,
                                                   const float* __restrict__ x,
                                                   const float* __restrict__ ab0, int N,
                                                   float* __restrict__ dinv,
                                                   float* __restrict__ agg1) {
  int i = blockIdx.x * blockDim.x + threadIdx.x;
  if (i >= N) return;
  float dv = rsqrtf((float)cnt[i] + 1.0f);
  dinv[i] = dv;
  float h0 = fmaf(x[i], ab0[0], ab0[1]);
  agg1[i] = h0 * dv * dv;
}

// ---- layer-1 edge aggregation (F_in = 1), h0 computed on the fly ----
__global__ void __launch_bounds__(256) k_a1(const int* __restrict__ src,
                                            const int* __restrict__ dst, int E,
                                            const float* __restrict__ x,
                                            const float* __restrict__ dinv,
                                            const float* __restrict__ ab0,
                                            float* __restrict__ agg1) {
  int e = blockIdx.x * blockDim.x + threadIdx.x;
  if (e >= E) return;
  int s = src[e], d = dst[e];
  float c = dinv[s] * dinv[d];
  float h0 = fmaf(x[s], ab0[0], ab0[1]);
  atomic_add_f(&agg1[d], c * h0);
}

// ---- generic edge aggregation: thread = (edge, 4-channel group) ----
template<int F>
__global__ void __launch_bounds__(256) k_agg(const int* __restrict__ src,
                                             const int* __restrict__ dst, int EG,
                                             const float* __restrict__ h,
                                             const float* __restrict__ dinv,
                                             float* __restrict__ agg) {
  int idx = blockIdx.x * blockDim.x + threadIdx.x;
  if (idx >= EG) return;
  constexpr int G = F / 4;             // float4 groups per edge
  constexpr int SH = (G == 2) ? 1 : 2; // log2(G)
  int e = idx >> SH;
  int q = idx & (G - 1);
  int s = src[e], d = dst[e];
  float c = dinv[s] * dinv[d];
  float4 hv = *(const float4*)(h + (size_t)s * F + q * 4);
  float* a = agg + (size_t)d * F + q * 4;
  atomic_add_f(a + 0, c * hv.x);
  atomic_add_f(a + 1, c * hv.y);
  atomic_add_f(a + 2, c * hv.z);
  atomic_add_f(a + 3, c * hv.w);
}

// ---- per-channel stats of y = gW + b (recompute y, accumulate sums) ----
template<int FI, int FO>
__global__ void __launch_bounds__(256) k_stats(const float* __restrict__ g,
                                               const float* __restrict__ W,
                                               const float* __restrict__ b, int N,
                                               float* __restrict__ sums) {
  __shared__ float Ws[FI * FO];
  __shared__ float bs[FO];
  for (int t = threadIdx.x; t < FI * FO; t += blockDim.x) Ws[t] = W[t];
  for (int t = threadIdx.x; t < FO; t += blockDim.x) bs[t] = b[t];
  __syncthreads();

  float s[FO], q[FO];
  #pragma unroll
  for (int j = 0; j < FO; j++) { s[j] = 0.f; q[j] = 0.f; }

  for (int i = blockIdx.x * blockDim.x + threadIdx.x; i < N; i += gridDim.x * blockDim.x) {
    float gv[FI];
    if constexpr (FI % 4 == 0) {
      const float4* g4 = (const float4*)(g + (size_t)i * FI);
      #pragma unroll
      for (int k = 0; k < FI / 4; k++) {
        float4 v = g4[k];
        gv[4 * k] = v.x; gv[4 * k + 1] = v.y; gv[4 * k + 2] = v.z; gv[4 * k + 3] = v.w;
      }
    } else {
      #pragma unroll
      for (int k = 0; k < FI; k++) gv[k] = g[(size_t)i * FI + k];
    }
    #pragma unroll
    for (int j = 0; j < FO; j++) {
      float y = bs[j];
      #pragma unroll
      for (int k = 0; k < FI; k++) y = fmaf(gv[k], Ws[k * FO + j], y);
      s[j] += y;
      q[j] = fmaf(y, y, q[j]);
    }
  }
  #pragma unroll
  for (int j = 0; j < FO; j++) {
    float sv = wave_sum(s[j]);
    float qv = wave_sum(q[j]);
    if ((threadIdx.x & 63) == 0) {
      atomic_add_f(&sums[j], sv);
      atomic_add_f(&sums[FO + j], qv);
    }
  }
}

// ---- fold BN into per-channel affine ----
template<int FO>
__global__ void __launch_bounds__(64) k_affine(const float* __restrict__ sums,
                                               const float* __restrict__ gamma,
                                               const float* __restrict__ beta, float invN,
                                               float* __restrict__ ab) {
  int j = threadIdx.x;
  if (j >= FO) return;
  float mu = sums[j] * invN;
  float var = fmaf(-mu, mu, sums[FO + j] * invN);
  float r = rsqrtf(var + EPS);
  float a = gamma[j] * r;
  ab[j] = a;
  ab[FO + j] = beta[j] - mu * a;
}

// ---- transform: h = relu((gW+b)*alpha+delta); also init next agg with h*dinv^2 ----
template<int FI, int FO>
__global__ void __launch_bounds__(256) k_transform(const float* __restrict__ g,
                                                   const float* __restrict__ W,
                                                   const float* __restrict__ b,
                                                   const float* __restrict__ ab,
                                                   const float* __restrict__ dinv, int N,
                                                   float* __restrict__ h,
                                                   float* __restrict__ aggn) {
  __shared__ float Ws[FI * FO];
  __shared__ float bs[FO];
  __shared__ float as2[2 * FO];
  for (int t = threadIdx.x; t < FI * FO; t += blockDim.x) Ws[t] = W[t];
  for (int t = threadIdx.x; t < FO; t += blockDim.x) bs[t] = b[t];
  for (int t = threadIdx.x; t < 2 * FO; t += blockDim.x) as2[t] = ab[t];
  __syncthreads();

  int i = blockIdx.x * blockDim.x + threadIdx.x;
  if (i >= N) return;

  float gv[FI];
  if constexpr (FI % 4 == 0) {
    const float4* g4 = (const float4*)(g + (size_t)i * FI);
    #pragma unroll
    for (int k = 0; k < FI / 4; k++) {
      float4 v = g4[k];
      gv[4 * k] = v.x; gv[4 * k + 1] = v.y; gv[4 * k + 2] = v.z; gv[4 * k + 3] = v.w;
    }
  } else {
    #pragma unroll
    for (int k = 0; k < FI; k++) gv[k] = g[(size_t)i * FI + k];
  }

  float dv = dinv[i];
  float dv2 = dv * dv;
  float hv[FO];
  #pragma unroll
  for (int j = 0; j < FO; j++) {
    float y = bs[j];
    #pragma unroll
    for (int k = 0; k < FI; k++) y = fmaf(gv[k], Ws[k * FO + j], y);
    hv[j] = fmaxf(fmaf(y, as2[j], as2[FO + j]), 0.f);
  }
  float4* h4 = (float4*)(h + (size_t)i * FO);
  float4* a4 = (float4*)(aggn + (size_t)i * FO);
  #pragma unroll
  for (int k = 0; k < FO / 4; k++) {
    float4 t;
    t.x = hv[4 * k]; t.y = hv[4 * k + 1]; t.z = hv[4 * k + 2]; t.w = hv[4 * k + 3];
    h4[k] = t;
    float4 u;
    u.x = t.x * dv2; u.y = t.y * dv2; u.z = t.z * dv2; u.w = t.w * dv2;
    a4[k] = u;
  }
}

// ---- layer-3 transform fused with segment-max pooling ----
template<int FI, int FO>
__global__ void __launch_bounds__(256) k_pool(const float* __restrict__ g,
                                              const float* __restrict__ W,
                                              const float* __restrict__ b,
                                              const float* __restrict__ ab,
                                              const int* __restrict__ batch, int N, int B,
                                              unsigned* __restrict__ pooled) {
  __shared__ float Ws[FI * FO];
  __shared__ float bs[FO];
  __shared__ float as2[2 * FO];
  __shared__ unsigned lpool[4 * FO];
  __shared__ int gid0s;
  for (int t = threadIdx.x; t < FI * FO; t += blockDim.x) Ws[t] = W[t];
  for (int t = threadIdx.x; t < FO; t += blockDim.x) bs[t] = b[t];
  for (int t = threadIdx.x; t < 2 * FO; t += blockDim.x) as2[t] = ab[t];
  if (threadIdx.x < 4 * FO) lpool[threadIdx.x] = 0u;
  int i0 = blockIdx.x * blockDim.x;
  if (threadIdx.x == 0) gid0s = batch[i0 < N ? i0 : (N - 1)];
  __syncthreads();
  int gid0 = gid0s;

  int i = i0 + threadIdx.x;
  if (i < N) {
    float gv[FI];
    const float4* g4 = (const float4*)(g + (size_t)i * FI);
    #pragma unroll
    for (int k = 0; k < FI / 4; k++) {
      float4 v = g4[k];
      gv[4 * k] = v.x; gv[4 * k + 1] = v.y; gv[4 * k + 2] = v.z; gv[4 * k + 3] = v.w;
    }
    int gid = batch[i];
    int slot = gid - gid0;
    #pragma unroll
    for (int j = 0; j < FO; j++) {
      float y = bs[j];
      #pragma unroll
      for (int k = 0; k < FI; k++) y = fmaf(gv[k], Ws[k * FO + j], y);
      float hv = fmaxf(fmaf(y, as2[j], as2[FO + j]), 0.f);
      unsigned u = __float_as_uint(hv);
      if (slot >= 0 && slot < 4) atomicMax(&lpool[slot * FO + j], u);
      else atomicMax(&pooled[(size_t)gid * FO + j], u);
    }
  }
  __syncthreads();
  for (int t = threadIdx.x; t < 4 * FO; t += blockDim.x) {
    unsigned v = lpool[t];
    int gid = gid0 + t / FO;
    if (v && gid < B) atomicMax(&pooled[(size_t)gid * FO + (t % FO)], v);
  }
}

// ---- final MLP: relu(relu(p@L1W+L1b)@L2W+L2b) ----
__global__ void __launch_bounds__(256) k_mlp(const unsigned* __restrict__ pooled,
                                             const float* __restrict__ W1,
                                             const float* __restrict__ b1,
                                             const float* __restrict__ W2,
                                             const float* __restrict__ b2, int B,
                                             float* __restrict__ out) {
  int gidx = blockIdx.x * blockDim.x + threadIdx.x;
  if (gidx >= B) return;
  float p[32];
  #pragma unroll
  for (int k = 0; k < 32; k++) p[k] = __uint_as_float(pooled[gidx * 32 + k]);
  float o0 = b2[0], o1 = b2[1];
  for (int j = 0; j < 64; j++) {
    float y = b1[j];
    #pragma unroll
    for (int k = 0; k < 32; k++) y = fmaf(p[k], W1[k * 64 + j], y);
    y = fmaxf(y, 0.f);
    o0 = fmaf(y, W2[j * 2 + 0], o0);
    o1 = fmaf(y, W2[j * 2 + 1], o1);
  }
  out[gidx * 2 + 0] = fmaxf(o0, 0.f);
  out[gidx * 2 + 1] = fmaxf(o1, 0.f);
}

extern "C" void kernel_launch(void* const* d_in, const int* in_sizes, int n_in,
                              void* d_out, int out_size, void* d_ws, size_t ws_size,
                              hipStream_t stream) {
  const float* x     = (const float*)d_in[0];
  const int*   ei    = (const int*)d_in[1];
  const int*   batch = (const int*)d_in[2];
  const float* bn0_g = (const float*)d_in[3];
  const float* bn0_b = (const float*)d_in[4];
  const float* W1    = (const float*)d_in[5];
  const float* b1    = (const float*)d_in[6];
  const float* bn1_g = (const float*)d_in[7];
  const float* bn1_b = (const float*)d_in[8];
  const float* W2    = (const float*)d_in[9];
  const float* b2    = (const float*)d_in[10];
  const float* bn2_g = (const float*)d_in[11];
  const float* bn2_b = (const float*)d_in[12];
  const float* W3    = (const float*)d_in[13];
  const float* b3    = (const float*)d_in[14];
  const float* bn3_g = (const float*)d_in[15];
  const float* bn3_b = (const float*)d_in[16];
  const float* L1W   = (const float*)d_in[17];
  const float* L1b   = (const float*)d_in[18];
  const float* L2W   = (const float*)d_in[19];
  const float* L2b   = (const float*)d_in[20];

  const int N = in_sizes[0];
  const int E = in_sizes[1] / 2;
  const int B = out_size / 2;
  const int* src = ei;
  const int* dst = ei + E;
  const float invN = 1.0f / (float)N;

  char* ws = (char*)d_ws;
  size_t off = 0;
  auto alloc = [&](size_t bytes) {
    char* p = ws + off;
    off += (bytes + 255) & ~(size_t)255;
    return p;
  };
  int*      cnt    = (int*)alloc((size_t)N * 4);
  float*    dinv   = (float*)alloc((size_t)N * 4);
  float*    agg1   = (float*)alloc((size_t)N * 4);
  float*    h1     = (float*)alloc((size_t)N * 8 * 4);
  float*    agg2   = (float*)alloc((size_t)N * 8 * 4);
  float*    h2     = (float*)alloc((size_t)N * 16 * 4);
  float*    agg3   = (float*)alloc((size_t)N * 16 * 4);
  unsigned* pooled = (unsigned*)alloc((size_t)B * 32 * 4);
  float*    stats  = (float*)alloc(1024 * 4);

  float* sums0 = stats + 0;    // 2
  float* ab0   = stats + 4;    // 2
  float* sums1 = stats + 8;    // 16
  float* ab1   = stats + 24;   // 16
  float* sums2 = stats + 40;   // 32
  float* ab2   = stats + 72;   // 32
  float* sums3 = stats + 104;  // 64
  float* ab3   = stats + 168;  // 64

  hipMemsetAsync(cnt, 0, (size_t)N * 4, stream);
  hipMemsetAsync(stats, 0, 1024 * 4, stream);
  hipMemsetAsync(pooled, 0, (size_t)B * 32 * 4, stream);

  const int T = 256;
  const int gN = (N + T - 1) / T;
  const int gE = (E + T - 1) / T;
  const int gS = 1024;  // grid-stride stats kernels

  k_deg<<<gE, T, 0, stream>>>(dst, E, cnt);
  k_s0<<<gS, T, 0, stream>>>(x, N, sums0);
  k_c0<<<1, 1, 0, stream>>>(sums0, bn0_g, bn0_b, invN, ab0);
  k_dinv_init<<<gN, T, 0, stream>>>(cnt, x, ab0, N, dinv, agg1);

  // layer 1
  k_a1<<<gE, T, 0, stream>>>(src, dst, E, x, dinv, ab0, agg1);
  k_stats<1, 8><<<gS, T, 0, stream>>>(agg1, W1, b1, N, sums1);
  k_affine<8><<<1, 64, 0, stream>>>(sums1, bn1_g, bn1_b, invN, ab1);
  k_transform<1, 8><<<gN, T, 0, stream>>>(agg1, W1, b1, ab1, dinv, N, h1, agg2);

  // layer 2
  {
    int EG = E * 2;  // 8 channels / 4
    k_agg<8><<<(EG + T - 1) / T, T, 0, stream>>>(src, dst, EG, h1, dinv, agg2);
  }
  k_stats<8, 16><<<gS, T, 0, stream>>>(agg2, W2, b2, N, sums2);
  k_affine<16><<<1, 64, 0, stream>>>(sums2, bn2_g, bn2_b, invN, ab2);
  k_transform<8, 16><<<gN, T, 0, stream>>>(agg2, W2, b2, ab2, dinv, N, h2, agg3);

  // layer 3
  {
    int EG = E * 4;  // 16 channels / 4
    k_agg<16><<<(EG + T - 1) / T, T, 0, stream>>>(src, dst, EG, h2, dinv, agg3);
  }
  k_stats<16, 32><<<gS, T, 0, stream>>>(agg3, W3, b3, N, sums3);
  k_affine<32><<<1, 64, 0, stream>>>(sums3, bn3_g, bn3_b, invN, ab3);
  k_pool<16, 32><<<gN, T, 0, stream>>>(agg3, W3, b3, ab3, batch, N, B, pooled);

  // final MLP
  k_mlp<<<(B + T - 1) / T, T, 0, stream>>>(pooled, L1W, L1b, L2W, L2b, B, (float*)d_out);
}

// Round 3
// 4236.330 us; speedup vs baseline: 1.5345x; 1.5345x over previous
//
#include <hip/hip_runtime.h>

#define EPS 1e-5f

__device__ __forceinline__ float wave_sum(float v) {
  #pragma unroll
  for (int o = 32; o > 0; o >>= 1) v += __shfl_down(v, o, 64);
  return v;
}

__device__ __forceinline__ void atomic_add_f(float* p, float v) {
  unsafeAtomicAdd(p, v);
}

// ---- degree count (before +1 self loop) ----
__global__ void __launch_bounds__(256) k_deg(const int* __restrict__ dst, int E,
                                             int* __restrict__ cnt) {
  int i = blockIdx.x * blockDim.x + threadIdx.x;
  if (i < E) atomicAdd(&cnt[dst[i]], 1);
}

// ---- dinv = rsqrt(deg+1) ----
__global__ void __launch_bounds__(256) k_dinv(const int* __restrict__ cnt, int N,
                                              float* __restrict__ dinv) {
  int i = blockIdx.x * blockDim.x + threadIdx.x;
  if (i < N) dinv[i] = rsqrtf((float)cnt[i] + 1.0f);
}

// ---- bn0 stats: sum, sumsq of x ----
__global__ void __launch_bounds__(256) k_s0(const float* __restrict__ x, int N,
                                            float* __restrict__ sums) {
  float s = 0.f, q = 0.f;
  for (int i = blockIdx.x * blockDim.x + threadIdx.x; i < N; i += gridDim.x * blockDim.x) {
    float v = x[i];
    s += v;
    q = fmaf(v, v, q);
  }
  s = wave_sum(s);
  q = wave_sum(q);
  if ((threadIdx.x & 63) == 0) { atomic_add_f(&sums[0], s); atomic_add_f(&sums[1], q); }
}

// ---- bn0 affine ----
__global__ void __launch_bounds__(64) k_c0(const float* __restrict__ sums,
                                           const float* __restrict__ g,
                                           const float* __restrict__ b, float invN,
                                           float* __restrict__ ab) {
  float mu = sums[0] * invN;
  float var = fmaf(-mu, mu, sums[1] * invN);
  float r = rsqrtf(var + EPS);
  float a = g[0] * r;
  ab[0] = a;
  ab[1] = b[0] - mu * a;
}

// ==== exclusive scan over cnt (N elems) -> off, per-2048 block sums -> bsum ====
__global__ void __launch_bounds__(256) k_scan1(const int* __restrict__ cnt, int N,
                                               int* __restrict__ off, int* __restrict__ bsum) {
  __shared__ int lds[256];
  int base = blockIdx.x * 2048 + threadIdx.x * 8;
  int v[8];
  int s = 0;
  #pragma unroll
  for (int k = 0; k < 8; k++) {
    int i = base + k;
    v[k] = (i < N) ? cnt[i] : 0;
    s += v[k];
  }
  lds[threadIdx.x] = s;
  __syncthreads();
  for (int o = 1; o < 256; o <<= 1) {
    int t2 = (threadIdx.x >= o) ? lds[threadIdx.x - o] : 0;
    __syncthreads();
    lds[threadIdx.x] += t2;
    __syncthreads();
  }
  int run = lds[threadIdx.x] - s;  // exclusive base for this thread
  #pragma unroll
  for (int k = 0; k < 8; k++) {
    int i = base + k;
    if (i < N) off[i] = run;
    run += v[k];
  }
  if (threadIdx.x == 255) bsum[blockIdx.x] = lds[255];
}

// single block: exclusive scan of up to 2048 block sums in place
__global__ void __launch_bounds__(256) k_scan2(int* __restrict__ bsum, int nb) {
  __shared__ int lds[256];
  int base = threadIdx.x * 8;
  int v[8];
  int s = 0;
  #pragma unroll
  for (int k = 0; k < 8; k++) {
    int i = base + k;
    v[k] = (i < nb) ? bsum[i] : 0;
    s += v[k];
  }
  lds[threadIdx.x] = s;
  __syncthreads();
  for (int o = 1; o < 256; o <<= 1) {
    int t2 = (threadIdx.x >= o) ? lds[threadIdx.x - o] : 0;
    __syncthreads();
    lds[threadIdx.x] += t2;
    __syncthreads();
  }
  int run = lds[threadIdx.x] - s;
  #pragma unroll
  for (int k = 0; k < 8; k++) {
    int i = base + k;
    if (i < nb) bsum[i] = run;
    run += v[k];
  }
}

// off[i] += bsum[i/2048]; cur[i] = off[i]
__global__ void __launch_bounds__(256) k_scan3(int* __restrict__ off,
                                               const int* __restrict__ bsum, int N,
                                               int* __restrict__ cur) {
  int i = blockIdx.x * blockDim.x + threadIdx.x;
  if (i >= N) return;
  int o = off[i] + bsum[i >> 11];
  off[i] = o;
  cur[i] = o;
}

// counting-sort scatter: csr[pos] = src[e], pos = cur[dst[e]]++
__global__ void __launch_bounds__(256) k_scatter(const int* __restrict__ src,
                                                 const int* __restrict__ dst, int E,
                                                 int* __restrict__ cur,
                                                 int* __restrict__ csr) {
  int e = blockIdx.x * blockDim.x + threadIdx.x;
  if (e >= E) return;
  int d = dst[e];
  int pos = atomicAdd(&cur[d], 1);
  csr[pos] = src[e];
}

// ---- layer-1 gather (F=1), h0 = x*a+b on the fly; self-loop folded in ----
__global__ void __launch_bounds__(256) k_gather1(const int* __restrict__ off,
                                                 const int* __restrict__ csr,
                                                 const float* __restrict__ x,
                                                 const float* __restrict__ dinv,
                                                 const float* __restrict__ ab0, int N, int E,
                                                 float* __restrict__ agg) {
  int d = blockIdx.x * blockDim.x + threadIdx.x;
  if (d >= N) return;
  float a = ab0[0], bb = ab0[1];
  int beg = off[d];
  int end = (d + 1 < N) ? off[d + 1] : E;
  float dv = dinv[d];
  float acc = fmaf(x[d], a, bb) * dv * dv;
  for (int e = beg; e < end; e++) {
    int s = csr[e];
    acc = fmaf(dinv[s] * dv, fmaf(x[s], a, bb), acc);
  }
  agg[d] = acc;
}

// ---- generic gather: thread = (node, float4 quad); self-loop folded in ----
template<int F>
__global__ void __launch_bounds__(256) k_gather(const int* __restrict__ off,
                                                const int* __restrict__ csr,
                                                const float* __restrict__ h,
                                                const float* __restrict__ dinv, int N, int E,
                                                float* __restrict__ agg) {
  constexpr int Q = F / 4;
  constexpr int SH = (Q == 2) ? 1 : 2;
  int t = blockIdx.x * blockDim.x + threadIdx.x;
  int d = t >> SH;
  if (d >= N) return;
  int q = t & (Q - 1);
  int beg = off[d];
  int end = (d + 1 < N) ? off[d + 1] : E;
  float dv = dinv[d];
  const float4* hp = (const float4*)h;
  float4 acc = hp[(size_t)d * Q + q];
  float c0 = dv * dv;
  acc.x *= c0; acc.y *= c0; acc.z *= c0; acc.w *= c0;
  for (int e = beg; e < end; e++) {
    int s = csr[e];
    float c = dinv[s] * dv;
    float4 v = hp[(size_t)s * Q + q];
    acc.x = fmaf(c, v.x, acc.x);
    acc.y = fmaf(c, v.y, acc.y);
    acc.z = fmaf(c, v.z, acc.z);
    acc.w = fmaf(c, v.w, acc.w);
  }
  ((float4*)agg)[(size_t)d * Q + q] = acc;
}

// ---- per-channel stats of y = gW + b ----
template<int FI, int FO>
__global__ void __launch_bounds__(256) k_stats(const float* __restrict__ g,
                                               const float* __restrict__ W,
                                               const float* __restrict__ b, int N,
                                               float* __restrict__ sums) {
  __shared__ float Ws[FI * FO];
  __shared__ float bs[FO];
  for (int t = threadIdx.x; t < FI * FO; t += blockDim.x) Ws[t] = W[t];
  for (int t = threadIdx.x; t < FO; t += blockDim.x) bs[t] = b[t];
  __syncthreads();

  float s[FO], q[FO];
  #pragma unroll
  for (int j = 0; j < FO; j++) { s[j] = 0.f; q[j] = 0.f; }

  for (int i = blockIdx.x * blockDim.x + threadIdx.x; i < N; i += gridDim.x * blockDim.x) {
    float gv[FI];
    if constexpr (FI % 4 == 0) {
      const float4* g4 = (const float4*)(g + (size_t)i * FI);
      #pragma unroll
      for (int k = 0; k < FI / 4; k++) {
        float4 v = g4[k];
        gv[4 * k] = v.x; gv[4 * k + 1] = v.y; gv[4 * k + 2] = v.z; gv[4 * k + 3] = v.w;
      }
    } else {
      #pragma unroll
      for (int k = 0; k < FI; k++) gv[k] = g[(size_t)i * FI + k];
    }
    #pragma unroll
    for (int j = 0; j < FO; j++) {
      float y = bs[j];
      #pragma unroll
      for (int k = 0; k < FI; k++) y = fmaf(gv[k], Ws[k * FO + j], y);
      s[j] += y;
      q[j] = fmaf(y, y, q[j]);
    }
  }
  #pragma unroll
  for (int j = 0; j < FO; j++) {
    float sv = wave_sum(s[j]);
    float qv = wave_sum(q[j]);
    if ((threadIdx.x & 63) == 0) {
      atomic_add_f(&sums[j], sv);
      atomic_add_f(&sums[FO + j], qv);
    }
  }
}

// ---- fold BN into per-channel affine ----
template<int FO>
__global__ void __launch_bounds__(64) k_affine(const float* __restrict__ sums,
                                               const float* __restrict__ gamma,
                                               const float* __restrict__ beta, float invN,
                                               float* __restrict__ ab) {
  int j = threadIdx.x;
  if (j >= FO) return;
  float mu = sums[j] * invN;
  float var = fmaf(-mu, mu, sums[FO + j] * invN);
  float r = rsqrtf(var + EPS);
  float a = gamma[j] * r;
  ab[j] = a;
  ab[FO + j] = beta[j] - mu * a;
}

// ---- transform: h = relu((gW+b)*alpha+delta) ----
template<int FI, int FO>
__global__ void __launch_bounds__(256) k_transform(const float* __restrict__ g,
                                                   const float* __restrict__ W,
                                                   const float* __restrict__ b,
                                                   const float* __restrict__ ab, int N,
                                                   float* __restrict__ h) {
  __shared__ float Ws[FI * FO];
  __shared__ float bs[FO];
  __shared__ float as2[2 * FO];
  for (int t = threadIdx.x; t < FI * FO; t += blockDim.x) Ws[t] = W[t];
  for (int t = threadIdx.x; t < FO; t += blockDim.x) bs[t] = b[t];
  for (int t = threadIdx.x; t < 2 * FO; t += blockDim.x) as2[t] = ab[t];
  __syncthreads();

  int i = blockIdx.x * blockDim.x + threadIdx.x;
  if (i >= N) return;

  float gv[FI];
  if constexpr (FI % 4 == 0) {
    const float4* g4 = (const float4*)(g + (size_t)i * FI);
    #pragma unroll
    for (int k = 0; k < FI / 4; k++) {
      float4 v = g4[k];
      gv[4 * k] = v.x; gv[4 * k + 1] = v.y; gv[4 * k + 2] = v.z; gv[4 * k + 3] = v.w;
    }
  } else {
    #pragma unroll
    for (int k = 0; k < FI; k++) gv[k] = g[(size_t)i * FI + k];
  }

  float hv[FO];
  #pragma unroll
  for (int j = 0; j < FO; j++) {
    float y = bs[j];
    #pragma unroll
    for (int k = 0; k < FI; k++) y = fmaf(gv[k], Ws[k * FO + j], y);
    hv[j] = fmaxf(fmaf(y, as2[j], as2[FO + j]), 0.f);
  }
  float4* h4 = (float4*)(h + (size_t)i * FO);
  #pragma unroll
  for (int k = 0; k < FO / 4; k++) {
    float4 t;
    t.x = hv[4 * k]; t.y = hv[4 * k + 1]; t.z = hv[4 * k + 2]; t.w = hv[4 * k + 3];
    h4[k] = t;
  }
}

// ---- layer-3 transform fused with segment-max pooling ----
template<int FI, int FO>
__global__ void __launch_bounds__(256) k_pool(const float* __restrict__ g,
                                              const float* __restrict__ W,
                                              const float* __restrict__ b,
                                              const float* __restrict__ ab,
                                              const int* __restrict__ batch, int N, int B,
                                              unsigned* __restrict__ pooled) {
  __shared__ float Ws[FI * FO];
  __shared__ float bs[FO];
  __shared__ float as2[2 * FO];
  __shared__ unsigned lpool[4 * FO];
  __shared__ int gid0s;
  for (int t = threadIdx.x; t < FI * FO; t += blockDim.x) Ws[t] = W[t];
  for (int t = threadIdx.x; t < FO; t += blockDim.x) bs[t] = b[t];
  for (int t = threadIdx.x; t < 2 * FO; t += blockDim.x) as2[t] = ab[t];
  if (threadIdx.x < 4 * FO) lpool[threadIdx.x] = 0u;
  int i0 = blockIdx.x * blockDim.x;
  if (threadIdx.x == 0) gid0s = batch[i0 < N ? i0 : (N - 1)];
  __syncthreads();
  int gid0 = gid0s;

  int i = i0 + threadIdx.x;
  if (i < N) {
    float gv[FI];
    const float4* g4 = (const float4*)(g + (size_t)i * FI);
    #pragma unroll
    for (int k = 0; k < FI / 4; k++) {
      float4 v = g4[k];
      gv[4 * k] = v.x; gv[4 * k + 1] = v.y; gv[4 * k + 2] = v.z; gv[4 * k + 3] = v.w;
    }
    int gid = batch[i];
    int slot = gid - gid0;
    #pragma unroll
    for (int j = 0; j < FO; j++) {
      float y = bs[j];
      #pragma unroll
      for (int k = 0; k < FI; k++) y = fmaf(gv[k], Ws[k * FO + j], y);
      float hv = fmaxf(fmaf(y, as2[j], as2[FO + j]), 0.f);
      unsigned u = __float_as_uint(hv);
      if (slot >= 0 && slot < 4) atomicMax(&lpool[slot * FO + j], u);
      else atomicMax(&pooled[(size_t)gid * FO + j], u);
    }
  }
  __syncthreads();
  for (int t = threadIdx.x; t < 4 * FO; t += blockDim.x) {
    unsigned v = lpool[t];
    int gid = gid0 + t / FO;
    if (v && gid < B) atomicMax(&pooled[(size_t)gid * FO + (t % FO)], v);
  }
}

// ---- final MLP ----
__global__ void __launch_bounds__(256) k_mlp(const unsigned* __restrict__ pooled,
                                             const float* __restrict__ W1,
                                             const float* __restrict__ b1,
                                             const float* __restrict__ W2,
                                             const float* __restrict__ b2, int B,
                                             float* __restrict__ out) {
  int gidx = blockIdx.x * blockDim.x + threadIdx.x;
  if (gidx >= B) return;
  float p[32];
  #pragma unroll
  for (int k = 0; k < 32; k++) p[k] = __uint_as_float(pooled[gidx * 32 + k]);
  float o0 = b2[0], o1 = b2[1];
  for (int j = 0; j < 64; j++) {
    float y = b1[j];
    #pragma unroll
    for (int k = 0; k < 32; k++) y = fmaf(p[k], W1[k * 64 + j], y);
    y = fmaxf(y, 0.f);
    o0 = fmaf(y, W2[j * 2 + 0], o0);
    o1 = fmaf(y, W2[j * 2 + 1], o1);
  }
  out[gidx * 2 + 0] = fmaxf(o0, 0.f);
  out[gidx * 2 + 1] = fmaxf(o1, 0.f);
}

extern "C" void kernel_launch(void* const* d_in, const int* in_sizes, int n_in,
                              void* d_out, int out_size, void* d_ws, size_t ws_size,
                              hipStream_t stream) {
  const float* x     = (const float*)d_in[0];
  const int*   ei    = (const int*)d_in[1];
  const int*   batch = (const int*)d_in[2];
  const float* bn0_g = (const float*)d_in[3];
  const float* bn0_b = (const float*)d_in[4];
  const float* W1    = (const float*)d_in[5];
  const float* b1    = (const float*)d_in[6];
  const float* bn1_g = (const float*)d_in[7];
  const float* bn1_b = (const float*)d_in[8];
  const float* W2    = (const float*)d_in[9];
  const float* b2    = (const float*)d_in[10];
  const float* bn2_g = (const float*)d_in[11];
  const float* bn2_b = (const float*)d_in[12];
  const float* W3    = (const float*)d_in[13];
  const float* b3    = (const float*)d_in[14];
  const float* bn3_g = (const float*)d_in[15];
  const float* bn3_b = (const float*)d_in[16];
  const float* L1W   = (const float*)d_in[17];
  const float* L1b   = (const float*)d_in[18];
  const float* L2W   = (const float*)d_in[19];
  const float* L2b   = (const float*)d_in[20];

  const int N = in_sizes[0];
  const int E = in_sizes[1] / 2;
  const int B = out_size / 2;
  const int* src = ei;
  const int* dst = ei + E;
  const float invN = 1.0f / (float)N;

  char* ws = (char*)d_ws;
  size_t off_b = 0;
  auto alloc = [&](size_t bytes) {
    char* p = ws + off_b;
    off_b += (bytes + 255) & ~(size_t)255;
    return p;
  };
  auto al = [](size_t b) { return (b + 255) & ~(size_t)255; };

  int*      cnt    = (int*)alloc((size_t)N * 4);      // reused as cursor after scan3
  int*      offv   = (int*)alloc((size_t)N * 4);
  float*    dinv   = (float*)alloc((size_t)N * 4);
  int*      bsum   = (int*)alloc(4096 * 4);
  int*      csr    = (int*)alloc((size_t)E * 4);

  // alias region: {agg1 + h1 + agg2} overlapped later by agg3
  size_t szA = al((size_t)N * 4) + al((size_t)N * 8 * 4) + al((size_t)N * 8 * 4);
  size_t szB = (size_t)N * 16 * 4;
  char*  region = alloc(szA > szB ? szA : szB);
  float* agg1 = (float*)region;
  float* h1   = (float*)(region + al((size_t)N * 4));
  float* agg2 = (float*)(region + al((size_t)N * 4) + al((size_t)N * 8 * 4));
  float* agg3 = (float*)region;  // live only after h1/agg1/agg2 are dead

  float*    h2     = (float*)alloc((size_t)N * 16 * 4);
  unsigned* pooled = (unsigned*)alloc((size_t)B * 32 * 4);
  float*    stats  = (float*)alloc(1024 * 4);

  float* sums0 = stats + 0;
  float* ab0   = stats + 4;
  float* sums1 = stats + 8;
  float* ab1   = stats + 24;
  float* sums2 = stats + 40;
  float* ab2   = stats + 72;
  float* sums3 = stats + 104;
  float* ab3   = stats + 168;

  int* cur = cnt;  // alias: cnt is dead after scan1 reads it (dinv computed first)

  hipMemsetAsync(cnt, 0, (size_t)N * 4, stream);
  hipMemsetAsync(stats, 0, 1024 * 4, stream);
  hipMemsetAsync(pooled, 0, (size_t)B * 32 * 4, stream);

  const int T = 256;
  const int gN = (N + T - 1) / T;
  const int gE = (E + T - 1) / T;
  const int gS = 1024;
  const int nbScan = (N + 2047) / 2048;

  // CSR build
  k_deg<<<gE, T, 0, stream>>>(dst, E, cnt);
  k_dinv<<<gN, T, 0, stream>>>(cnt, N, dinv);
  k_s0<<<gS, T, 0, stream>>>(x, N, sums0);
  k_c0<<<1, 1, 0, stream>>>(sums0, bn0_g, bn0_b, invN, ab0);
  k_scan1<<<nbScan, T, 0, stream>>>(cnt, N, offv, bsum);
  k_scan2<<<1, T, 0, stream>>>(bsum, nbScan);
  k_scan3<<<gN, T, 0, stream>>>(offv, bsum, N, cur);
  k_scatter<<<gE, T, 0, stream>>>(src, dst, E, cur, csr);

  // layer 1 (FI=1 -> FO=8)
  k_gather1<<<gN, T, 0, stream>>>(offv, csr, x, dinv, ab0, N, E, agg1);
  k_stats<1, 8><<<gS, T, 0, stream>>>(agg1, W1, b1, N, sums1);
  k_affine<8><<<1, 64, 0, stream>>>(sums1, bn1_g, bn1_b, invN, ab1);
  k_transform<1, 8><<<gN, T, 0, stream>>>(agg1, W1, b1, ab1, N, h1);

  // layer 2 (FI=8 -> FO=16)
  k_gather<8><<<(N * 2 + T - 1) / T, T, 0, stream>>>(offv, csr, h1, dinv, N, E, agg2);
  k_stats<8, 16><<<gS, T, 0, stream>>>(agg2, W2, b2, N, sums2);
  k_affine<16><<<1, 64, 0, stream>>>(sums2, bn2_g, bn2_b, invN, ab2);
  k_transform<8, 16><<<gN, T, 0, stream>>>(agg2, W2, b2, ab2, N, h2);

  // layer 3 (FI=16 -> FO=32); agg3 aliases the now-dead agg1/h1/agg2 region
  k_gather<16><<<(N * 4 + T - 1) / T, T, 0, stream>>>(offv, csr, h2, dinv, N, E, agg3);
  k_stats<16, 32><<<gS, T, 0, stream>>>(agg3, W3, b3, N, sums3);
  k_affine<32><<<1, 64, 0, stream>>>(sums3, bn3_g, bn3_b, invN, ab3);
  k_pool<16, 32><<<gN, T, 0, stream>>>(agg3, W3, b3, ab3, batch, N, B, pooled);

  // final MLP
  k_mlp<<<(B + T - 1) / T, T, 0, stream>>>(pooled, L1W, L1b, L2W, L2b, B, (float*)d_out);
}

// Round 4
// 1915.897 us; speedup vs baseline: 3.3929x; 2.2111x over previous
//
#include <hip/hip_runtime.h>

#define EPS 1e-5f

__device__ __forceinline__ float wave_sum(float v) {
  #pragma unroll
  for (int o = 32; o > 0; o >>= 1) v += __shfl_down(v, o, 64);
  return v;
}

__device__ __forceinline__ void atomic_add_f(float* p, float v) {
  unsafeAtomicAdd(p, v);
}

// ---- degree count (before +1 self loop) ----
__global__ void __launch_bounds__(256) k_deg(const int* __restrict__ dst, int E,
                                             int* __restrict__ cnt) {
  int i = blockIdx.x * blockDim.x + threadIdx.x;
  if (i < E) atomicAdd(&cnt[dst[i]], 1);
}

// ---- dinv = rsqrt(deg+1) ----
__global__ void __launch_bounds__(256) k_dinv(const int* __restrict__ cnt, int N,
                                              float* __restrict__ dinv) {
  int i = blockIdx.x * blockDim.x + threadIdx.x;
  if (i < N) dinv[i] = rsqrtf((float)cnt[i] + 1.0f);
}

// ---- bn0 stats: sum, sumsq of x ----
__global__ void __launch_bounds__(256) k_s0(const float* __restrict__ x, int N,
                                            float* __restrict__ sums) {
  float s = 0.f, q = 0.f;
  for (int i = blockIdx.x * blockDim.x + threadIdx.x; i < N; i += gridDim.x * blockDim.x) {
    float v = x[i];
    s += v;
    q = fmaf(v, v, q);
  }
  s = wave_sum(s);
  q = wave_sum(q);
  if ((threadIdx.x & 63) == 0) { atomic_add_f(&sums[0], s); atomic_add_f(&sums[1], q); }
}

// ---- bn0 affine ----
__global__ void __launch_bounds__(64) k_c0(const float* __restrict__ sums,
                                           const float* __restrict__ g,
                                           const float* __restrict__ b, float invN,
                                           float* __restrict__ ab) {
  float mu = sums[0] * invN;
  float var = fmaf(-mu, mu, sums[1] * invN);
  float r = rsqrtf(var + EPS);
  float a = g[0] * r;
  ab[0] = a;
  ab[1] = b[0] - mu * a;
}

// ==== exclusive scan over cnt (N elems) -> off, per-2048 block sums -> bsum ====
__global__ void __launch_bounds__(256) k_scan1(const int* __restrict__ cnt, int N,
                                               int* __restrict__ off, int* __restrict__ bsum) {
  __shared__ int lds[256];
  int base = blockIdx.x * 2048 + threadIdx.x * 8;
  int v[8];
  int s = 0;
  #pragma unroll
  for (int k = 0; k < 8; k++) {
    int i = base + k;
    v[k] = (i < N) ? cnt[i] : 0;
    s += v[k];
  }
  lds[threadIdx.x] = s;
  __syncthreads();
  for (int o = 1; o < 256; o <<= 1) {
    int t2 = (threadIdx.x >= o) ? lds[threadIdx.x - o] : 0;
    __syncthreads();
    lds[threadIdx.x] += t2;
    __syncthreads();
  }
  int run = lds[threadIdx.x] - s;  // exclusive base for this thread
  #pragma unroll
  for (int k = 0; k < 8; k++) {
    int i = base + k;
    if (i < N) off[i] = run;
    run += v[k];
  }
  if (threadIdx.x == 255) bsum[blockIdx.x] = lds[255];
}

// single block: exclusive scan of up to 2048 block sums in place
__global__ void __launch_bounds__(256) k_scan2(int* __restrict__ bsum, int nb) {
  __shared__ int lds[256];
  int base = threadIdx.x * 8;
  int v[8];
  int s = 0;
  #pragma unroll
  for (int k = 0; k < 8; k++) {
    int i = base + k;
    v[k] = (i < nb) ? bsum[i] : 0;
    s += v[k];
  }
  lds[threadIdx.x] = s;
  __syncthreads();
  for (int o = 1; o < 256; o <<= 1) {
    int t2 = (threadIdx.x >= o) ? lds[threadIdx.x - o] : 0;
    __syncthreads();
    lds[threadIdx.x] += t2;
    __syncthreads();
  }
  int run = lds[threadIdx.x] - s;
  #pragma unroll
  for (int k = 0; k < 8; k++) {
    int i = base + k;
    if (i < nb) bsum[i] = run;
    run += v[k];
  }
}

// off[i] += bsum[i/2048]; cur[i] = off[i]
__global__ void __launch_bounds__(256) k_scan3(int* __restrict__ off,
                                               const int* __restrict__ bsum, int N,
                                               int* __restrict__ cur) {
  int i = blockIdx.x * blockDim.x + threadIdx.x;
  if (i >= N) return;
  int o = off[i] + bsum[i >> 11];
  off[i] = o;
  cur[i] = o;
}

// counting-sort scatter: csr[pos] = src[e], pos = cur[dst[e]]++
__global__ void __launch_bounds__(256) k_scatter(const int* __restrict__ src,
                                                 const int* __restrict__ dst, int E,
                                                 int* __restrict__ cur,
                                                 int* __restrict__ csr) {
  int e = blockIdx.x * blockDim.x + threadIdx.x;
  if (e >= E) return;
  int d = dst[e];
  int pos = atomicAdd(&cur[d], 1);
  csr[pos] = src[e];
}

// ---- layer-1 gather (F=1), h0 = x*a+b on the fly; self-loop folded in ----
__global__ void __launch_bounds__(256) k_gather1(const int* __restrict__ off,
                                                 const int* __restrict__ csr,
                                                 const float* __restrict__ x,
                                                 const float* __restrict__ dinv,
                                                 const float* __restrict__ ab0, int N, int E,
                                                 float* __restrict__ agg) {
  int d = blockIdx.x * blockDim.x + threadIdx.x;
  if (d >= N) return;
  float a = ab0[0], bb = ab0[1];
  int beg = off[d];
  int end = (d + 1 < N) ? off[d + 1] : E;
  float dv = dinv[d];
  float acc = fmaf(x[d], a, bb) * dv * dv;
  for (int e = beg; e < end; e++) {
    int s = csr[e];
    acc = fmaf(dinv[s] * dv, fmaf(x[s], a, bb), acc);
  }
  agg[d] = acc;
}

// ---- generic gather: thread = (node, float4 quad); self-loop folded in ----
template<int F>
__global__ void __launch_bounds__(256) k_gather(const int* __restrict__ off,
                                                const int* __restrict__ csr,
                                                const float* __restrict__ h,
                                                const float* __restrict__ dinv, int N, int E,
                                                float* __restrict__ agg) {
  constexpr int Q = F / 4;
  constexpr int SH = (Q == 2) ? 1 : 2;
  int t = blockIdx.x * blockDim.x + threadIdx.x;
  int d = t >> SH;
  if (d >= N) return;
  int q = t & (Q - 1);
  int beg = off[d];
  int end = (d + 1 < N) ? off[d + 1] : E;
  float dv = dinv[d];
  const float4* hp = (const float4*)h;
  float4 acc = hp[(size_t)d * Q + q];
  float c0 = dv * dv;
  acc.x *= c0; acc.y *= c0; acc.z *= c0; acc.w *= c0;
  for (int e = beg; e < end; e++) {
    int s = csr[e];
    float c = dinv[s] * dv;
    float4 v = hp[(size_t)s * Q + q];
    acc.x = fmaf(c, v.x, acc.x);
    acc.y = fmaf(c, v.y, acc.y);
    acc.z = fmaf(c, v.z, acc.z);
    acc.w = fmaf(c, v.w, acc.w);
  }
  ((float4*)agg)[(size_t)d * Q + q] = acc;
}

// ==== per-channel stats of y = gW + b, channel-group split (8 channels/block) ====
// blockIdx.y selects channels [8*y, 8*y+8). Per-thread state: four named float4s.
// No indexable arrays in the hot loop -> cannot spill to scratch.
#define STATS_STEP(GK, K)                                   \
  {                                                         \
    const float gk_ = (GK);                                 \
    const float* wr_ = Wsh + (K) * 8;                       \
    y0.x = fmaf(gk_, wr_[0], y0.x);                         \
    y0.y = fmaf(gk_, wr_[1], y0.y);                         \
    y0.z = fmaf(gk_, wr_[2], y0.z);                         \
    y0.w = fmaf(gk_, wr_[3], y0.w);                         \
    y1.x = fmaf(gk_, wr_[4], y1.x);                         \
    y1.y = fmaf(gk_, wr_[5], y1.y);                         \
    y1.z = fmaf(gk_, wr_[6], y1.z);                         \
    y1.w = fmaf(gk_, wr_[7], y1.w);                         \
  }

template<int FI, int FO>
__global__ void __launch_bounds__(256) k_stats8(const float* __restrict__ g,
                                                const float* __restrict__ W,
                                                const float* __restrict__ b, int N,
                                                float* __restrict__ sums) {
  const int j0 = blockIdx.y * 8;
  __shared__ float Wsh[FI * 8];
  __shared__ float bsh[8];
  __shared__ float red[4][16];
  for (int t = threadIdx.x; t < FI * 8; t += blockDim.x) {
    int k = t >> 3, jj = t & 7;
    Wsh[t] = W[k * FO + j0 + jj];
  }
  if (threadIdx.x < 8) bsh[threadIdx.x] = b[j0 + threadIdx.x];
  __syncthreads();

  float4 s0 = {0.f, 0.f, 0.f, 0.f}, s1 = {0.f, 0.f, 0.f, 0.f};
  float4 q0 = {0.f, 0.f, 0.f, 0.f}, q1 = {0.f, 0.f, 0.f, 0.f};

  for (int i = blockIdx.x * blockDim.x + threadIdx.x; i < N; i += gridDim.x * blockDim.x) {
    float4 y0 = {bsh[0], bsh[1], bsh[2], bsh[3]};
    float4 y1 = {bsh[4], bsh[5], bsh[6], bsh[7]};
    const float* gp = g + (size_t)i * FI;
    if constexpr (FI == 1) {
      STATS_STEP(gp[0], 0)
    } else if constexpr (FI == 8) {
      float4 ga = *(const float4*)gp;
      float4 gb = *(const float4*)(gp + 4);
      STATS_STEP(ga.x, 0) STATS_STEP(ga.y, 1) STATS_STEP(ga.z, 2) STATS_STEP(ga.w, 3)
      STATS_STEP(gb.x, 4) STATS_STEP(gb.y, 5) STATS_STEP(gb.z, 6) STATS_STEP(gb.w, 7)
    } else {
      float4 ga = *(const float4*)gp;
      float4 gb = *(const float4*)(gp + 4);
      float4 gc = *(const float4*)(gp + 8);
      float4 gd = *(const float4*)(gp + 12);
      STATS_STEP(ga.x, 0)  STATS_STEP(ga.y, 1)  STATS_STEP(ga.z, 2)  STATS_STEP(ga.w, 3)
      STATS_STEP(gb.x, 4)  STATS_STEP(gb.y, 5)  STATS_STEP(gb.z, 6)  STATS_STEP(gb.w, 7)
      STATS_STEP(gc.x, 8)  STATS_STEP(gc.y, 9)  STATS_STEP(gc.z, 10) STATS_STEP(gc.w, 11)
      STATS_STEP(gd.x, 12) STATS_STEP(gd.y, 13) STATS_STEP(gd.z, 14) STATS_STEP(gd.w, 15)
    }
    s0.x += y0.x; s0.y += y0.y; s0.z += y0.z; s0.w += y0.w;
    s1.x += y1.x; s1.y += y1.y; s1.z += y1.z; s1.w += y1.w;
    q0.x = fmaf(y0.x, y0.x, q0.x); q0.y = fmaf(y0.y, y0.y, q0.y);
    q0.z = fmaf(y0.z, y0.z, q0.z); q0.w = fmaf(y0.w, y0.w, q0.w);
    q1.x = fmaf(y1.x, y1.x, q1.x); q1.y = fmaf(y1.y, y1.y, q1.y);
    q1.z = fmaf(y1.z, y1.z, q1.z); q1.w = fmaf(y1.w, y1.w, q1.w);
  }

  float vals[16] = {s0.x, s0.y, s0.z, s0.w, s1.x, s1.y, s1.z, s1.w,
                    q0.x, q0.y, q0.z, q0.w, q1.x, q1.y, q1.z, q1.w};
  #pragma unroll
  for (int c = 0; c < 16; c++) vals[c] = wave_sum(vals[c]);

  int wid = threadIdx.x >> 6, lane = threadIdx.x & 63;
  if (lane == 0) {
    #pragma unroll
    for (int c = 0; c < 16; c++) red[wid][c] = vals[c];
  }
  __syncthreads();
  if (threadIdx.x < 16) {
    int c = threadIdx.x;
    float t = red[0][c] + red[1][c] + red[2][c] + red[3][c];
    int j = j0 + (c & 7);
    atomic_add_f((c < 8) ? &sums[j] : &sums[FO + j], t);
  }
}

// ---- fold BN into per-channel affine ----
template<int FO>
__global__ void __launch_bounds__(64) k_affine(const float* __restrict__ sums,
                                               const float* __restrict__ gamma,
                                               const float* __restrict__ beta, float invN,
                                               float* __restrict__ ab) {
  int j = threadIdx.x;
  if (j >= FO) return;
  float mu = sums[j] * invN;
  float var = fmaf(-mu, mu, sums[FO + j] * invN);
  float r = rsqrtf(var + EPS);
  float a = gamma[j] * r;
  ab[j] = a;
  ab[FO + j] = beta[j] - mu * a;
}

// ---- transform: h = relu((gW+b)*alpha+delta) ----
template<int FI, int FO>
__global__ void __launch_bounds__(256) k_transform(const float* __restrict__ g,
                                                   const float* __restrict__ W,
                                                   const float* __restrict__ b,
                                                   const float* __restrict__ ab, int N,
                                                   float* __restrict__ h) {
  __shared__ float Ws[FI * FO];
  __shared__ float bs[FO];
  __shared__ float as2[2 * FO];
  for (int t = threadIdx.x; t < FI * FO; t += blockDim.x) Ws[t] = W[t];
  for (int t = threadIdx.x; t < FO; t += blockDim.x) bs[t] = b[t];
  for (int t = threadIdx.x; t < 2 * FO; t += blockDim.x) as2[t] = ab[t];
  __syncthreads();

  int i = blockIdx.x * blockDim.x + threadIdx.x;
  if (i >= N) return;

  float gv[FI];
  if constexpr (FI % 4 == 0) {
    const float4* g4 = (const float4*)(g + (size_t)i * FI);
    #pragma unroll
    for (int k = 0; k < FI / 4; k++) {
      float4 v = g4[k];
      gv[4 * k] = v.x; gv[4 * k + 1] = v.y; gv[4 * k + 2] = v.z; gv[4 * k + 3] = v.w;
    }
  } else {
    #pragma unroll
    for (int k = 0; k < FI; k++) gv[k] = g[(size_t)i * FI + k];
  }

  // process output channels in quads; no persistent hv array
  #pragma unroll
  for (int jq = 0; jq < FO / 4; jq++) {
    float4 y = {bs[4 * jq], bs[4 * jq + 1], bs[4 * jq + 2], bs[4 * jq + 3]};
    #pragma unroll
    for (int k = 0; k < FI; k++) {
      float gk = gv[k];
      const float* wr = Ws + k * FO + 4 * jq;
      y.x = fmaf(gk, wr[0], y.x);
      y.y = fmaf(gk, wr[1], y.y);
      y.z = fmaf(gk, wr[2], y.z);
      y.w = fmaf(gk, wr[3], y.w);
    }
    float4 o;
    o.x = fmaxf(fmaf(y.x, as2[4 * jq + 0], as2[FO + 4 * jq + 0]), 0.f);
    o.y = fmaxf(fmaf(y.y, as2[4 * jq + 1], as2[FO + 4 * jq + 1]), 0.f);
    o.z = fmaxf(fmaf(y.z, as2[4 * jq + 2], as2[FO + 4 * jq + 2]), 0.f);
    o.w = fmaxf(fmaf(y.w, as2[4 * jq + 3], as2[FO + 4 * jq + 3]), 0.f);
    ((float4*)(h + (size_t)i * FO))[jq] = o;
  }
}

// ---- layer-3 transform fused with segment-max pooling ----
template<int FI, int FO>
__global__ void __launch_bounds__(256) k_pool(const float* __restrict__ g,
                                              const float* __restrict__ W,
                                              const float* __restrict__ b,
                                              const float* __restrict__ ab,
                                              const int* __restrict__ batch, int N, int B,
                                              unsigned* __restrict__ pooled) {
  __shared__ float Ws[FI * FO];
  __shared__ float bs[FO];
  __shared__ float as2[2 * FO];
  __shared__ unsigned lpool[4 * FO];
  __shared__ int gid0s;
  for (int t = threadIdx.x; t < FI * FO; t += blockDim.x) Ws[t] = W[t];
  for (int t = threadIdx.x; t < FO; t += blockDim.x) bs[t] = b[t];
  for (int t = threadIdx.x; t < 2 * FO; t += blockDim.x) as2[t] = ab[t];
  if (threadIdx.x < 4 * FO) lpool[threadIdx.x] = 0u;
  int i0 = blockIdx.x * blockDim.x;
  if (threadIdx.x == 0) gid0s = batch[i0 < N ? i0 : (N - 1)];
  __syncthreads();
  int gid0 = gid0s;

  int i = i0 + threadIdx.x;
  if (i < N) {
    float gv[FI];
    const float4* g4 = (const float4*)(g + (size_t)i * FI);
    #pragma unroll
    for (int k = 0; k < FI / 4; k++) {
      float4 v = g4[k];
      gv[4 * k] = v.x; gv[4 * k + 1] = v.y; gv[4 * k + 2] = v.z; gv[4 * k + 3] = v.w;
    }
    int gid = batch[i];
    int slot = gid - gid0;
    #pragma unroll
    for (int j = 0; j < FO; j++) {
      float y = bs[j];
      #pragma unroll
      for (int k = 0; k < FI; k++) y = fmaf(gv[k], Ws[k * FO + j], y);
      float hv = fmaxf(fmaf(y, as2[j], as2[FO + j]), 0.f);
      unsigned u = __float_as_uint(hv);
      if (slot >= 0 && slot < 4) atomicMax(&lpool[slot * FO + j], u);
      else atomicMax(&pooled[(size_t)gid * FO + j], u);
    }
  }
  __syncthreads();
  for (int t = threadIdx.x; t < 4 * FO; t += blockDim.x) {
    unsigned v = lpool[t];
    int gid = gid0 + t / FO;
    if (v && gid < B) atomicMax(&pooled[(size_t)gid * FO + (t % FO)], v);
  }
}

// ---- final MLP ----
__global__ void __launch_bounds__(256) k_mlp(const unsigned* __restrict__ pooled,
                                             const float* __restrict__ W1,
                                             const float* __restrict__ b1,
                                             const float* __restrict__ W2,
                                             const float* __restrict__ b2, int B,
                                             float* __restrict__ out) {
  int gidx = blockIdx.x * blockDim.x + threadIdx.x;
  if (gidx >= B) return;
  float p[32];
  #pragma unroll
  for (int k = 0; k < 32; k++) p[k] = __uint_as_float(pooled[gidx * 32 + k]);
  float o0 = b2[0], o1 = b2[1];
  for (int j = 0; j < 64; j++) {
    float y = b1[j];
    #pragma unroll
    for (int k = 0; k < 32; k++) y = fmaf(p[k], W1[k * 64 + j], y);
    y = fmaxf(y, 0.f);
    o0 = fmaf(y, W2[j * 2 + 0], o0);
    o1 = fmaf(y, W2[j * 2 + 1], o1);
  }
  out[gidx * 2 + 0] = fmaxf(o0, 0.f);
  out[gidx * 2 + 1] = fmaxf(o1, 0.f);
}

extern "C" void kernel_launch(void* const* d_in, const int* in_sizes, int n_in,
                              void* d_out, int out_size, void* d_ws, size_t ws_size,
                              hipStream_t stream) {
  const float* x     = (const float*)d_in[0];
  const int*   ei    = (const int*)d_in[1];
  const int*   batch = (const int*)d_in[2];
  const float* bn0_g = (const float*)d_in[3];
  const float* bn0_b = (const float*)d_in[4];
  const float* W1    = (const float*)d_in[5];
  const float* b1    = (const float*)d_in[6];
  const float* bn1_g = (const float*)d_in[7];
  const float* bn1_b = (const float*)d_in[8];
  const float* W2    = (const float*)d_in[9];
  const float* b2    = (const float*)d_in[10];
  const float* bn2_g = (const float*)d_in[11];
  const float* bn2_b = (const float*)d_in[12];
  const float* W3    = (const float*)d_in[13];
  const float* b3    = (const float*)d_in[14];
  const float* bn3_g = (const float*)d_in[15];
  const float* bn3_b = (const float*)d_in[16];
  const float* L1W   = (const float*)d_in[17];
  const float* L1b   = (const float*)d_in[18];
  const float* L2W   = (const float*)d_in[19];
  const float* L2b   = (const float*)d_in[20];

  const int N = in_sizes[0];
  const int E = in_sizes[1] / 2;
  const int B = out_size / 2;
  const int* src = ei;
  const int* dst = ei + E;
  const float invN = 1.0f / (float)N;

  char* ws = (char*)d_ws;
  size_t off_b = 0;
  auto alloc = [&](size_t bytes) {
    char* p = ws + off_b;
    off_b += (bytes + 255) & ~(size_t)255;
    return p;
  };
  auto al = [](size_t b) { return (b + 255) & ~(size_t)255; };

  int*      cnt    = (int*)alloc((size_t)N * 4);      // reused as cursor after scan3
  int*      offv   = (int*)alloc((size_t)N * 4);
  float*    dinv   = (float*)alloc((size_t)N * 4);
  int*      bsum   = (int*)alloc(4096 * 4);
  int*      csr    = (int*)alloc((size_t)E * 4);

  // alias region: {agg1 + h1 + agg2} overlapped later by agg3
  size_t szA = al((size_t)N * 4) + al((size_t)N * 8 * 4) + al((size_t)N * 8 * 4);
  size_t szB = (size_t)N * 16 * 4;
  char*  region = alloc(szA > szB ? szA : szB);
  float* agg1 = (float*)region;
  float* h1   = (float*)(region + al((size_t)N * 4));
  float* agg2 = (float*)(region + al((size_t)N * 4) + al((size_t)N * 8 * 4));
  float* agg3 = (float*)region;  // live only after h1/agg1/agg2 are dead

  float*    h2     = (float*)alloc((size_t)N * 16 * 4);
  unsigned* pooled = (unsigned*)alloc((size_t)B * 32 * 4);
  float*    stats  = (float*)alloc(1024 * 4);

  float* sums0 = stats + 0;
  float* ab0   = stats + 4;
  float* sums1 = stats + 8;
  float* ab1   = stats + 24;
  float* sums2 = stats + 40;
  float* ab2   = stats + 72;
  float* sums3 = stats + 104;
  float* ab3   = stats + 168;

  int* cur = cnt;  // alias: cnt is dead after scan1 reads it

  hipMemsetAsync(cnt, 0, (size_t)N * 4, stream);
  hipMemsetAsync(stats, 0, 1024 * 4, stream);
  hipMemsetAsync(pooled, 0, (size_t)B * 32 * 4, stream);

  const int T = 256;
  const int gN = (N + T - 1) / T;
  const int gE = (E + T - 1) / T;
  const int gS = 1024;
  const int gX = 512;  // stats x-grid (grid-stride)
  const int nbScan = (N + 2047) / 2048;

  // CSR build
  k_deg<<<gE, T, 0, stream>>>(dst, E, cnt);
  k_dinv<<<gN, T, 0, stream>>>(cnt, N, dinv);
  k_s0<<<gS, T, 0, stream>>>(x, N, sums0);
  k_c0<<<1, 1, 0, stream>>>(sums0, bn0_g, bn0_b, invN, ab0);
  k_scan1<<<nbScan, T, 0, stream>>>(cnt, N, offv, bsum);
  k_scan2<<<1, T, 0, stream>>>(bsum, nbScan);
  k_scan3<<<gN, T, 0, stream>>>(offv, bsum, N, cur);
  k_scatter<<<gE, T, 0, stream>>>(src, dst, E, cur, csr);

  // layer 1 (FI=1 -> FO=8)
  k_gather1<<<gN, T, 0, stream>>>(offv, csr, x, dinv, ab0, N, E, agg1);
  k_stats8<1, 8><<<dim3(gX, 1), T, 0, stream>>>(agg1, W1, b1, N, sums1);
  k_affine<8><<<1, 64, 0, stream>>>(sums1, bn1_g, bn1_b, invN, ab1);
  k_transform<1, 8><<<gN, T, 0, stream>>>(agg1, W1, b1, ab1, N, h1);

  // layer 2 (FI=8 -> FO=16)
  k_gather<8><<<(N * 2 + T - 1) / T, T, 0, stream>>>(offv, csr, h1, dinv, N, E, agg2);
  k_stats8<8, 16><<<dim3(gX, 2), T, 0, stream>>>(agg2, W2, b2, N, sums2);
  k_affine<16><<<1, 64, 0, stream>>>(sums2, bn2_g, bn2_b, invN, ab2);
  k_transform<8, 16><<<gN, T, 0, stream>>>(agg2, W2, b2, ab2, N, h2);

  // layer 3 (FI=16 -> FO=32); agg3 aliases the now-dead agg1/h1/agg2 region
  k_gather<16><<<(N * 4 + T - 1) / T, T, 0, stream>>>(offv, csr, h2, dinv, N, E, agg3);
  k_stats8<16, 32><<<dim3(gX, 4), T, 0, stream>>>(agg3, W3, b3, N, sums3);
  k_affine<32><<<1, 64, 0, stream>>>(sums3, bn3_g, bn3_b, invN, ab3);
  k_pool<16, 32><<<gN, T, 0, stream>>>(agg3, W3, b3, ab3, batch, N, B, pooled);

  // final MLP
  k_mlp<<<(B + T - 1) / T, T, 0, stream>>>(pooled, L1W, L1b, L2W, L2b, B, (float*)d_out);
}

// Round 5
// 1671.628 us; speedup vs baseline: 3.8887x; 1.1461x over previous
//
#include <hip/hip_runtime.h>

#define EPS 1e-5f
#define CHUNK 16384
#define NB 64

typedef unsigned long long u64;

__device__ __forceinline__ float wave_sum(float v) {
  #pragma unroll
  for (int o = 32; o > 0; o >>= 1) v += __shfl_down(v, o, 64);
  return v;
}

__device__ __forceinline__ void atomic_add_f(float* p, float v) {
  unsafeAtomicAdd(p, v);
}

// ---- bn0 stats: sum, sumsq of x ----
__global__ void __launch_bounds__(256) k_s0(const float* __restrict__ x, int N,
                                            float* __restrict__ sums) {
  float s = 0.f, q = 0.f;
  for (int i = blockIdx.x * blockDim.x + threadIdx.x; i < N; i += gridDim.x * blockDim.x) {
    float v = x[i];
    s += v;
    q = fmaf(v, v, q);
  }
  s = wave_sum(s);
  q = wave_sum(q);
  if ((threadIdx.x & 63) == 0) { atomic_add_f(&sums[0], s); atomic_add_f(&sums[1], q); }
}

// ---- bn0 affine ----
__global__ void __launch_bounds__(64) k_c0(const float* __restrict__ sums,
                                           const float* __restrict__ g,
                                           const float* __restrict__ b, float invN,
                                           float* __restrict__ ab) {
  float mu = sums[0] * invN;
  float var = fmaf(-mu, mu, sums[1] * invN);
  float r = rsqrtf(var + EPS);
  float a = g[0] * r;
  ab[0] = a;
  ab[1] = b[0] - mu * a;
}

// ==== Phase A: per-chunk bucket histogram (bucket = dst >> shift) ====
__global__ void __launch_bounds__(256) k_hist(const int* __restrict__ dst, int E, int nblk,
                                              int shift, int* __restrict__ histG) {
  __shared__ int h[NB];
  if (threadIdx.x < NB) h[threadIdx.x] = 0;
  __syncthreads();
  int base = blockIdx.x * CHUNK;
  int end = base + CHUNK < E ? base + CHUNK : E;
  for (int i = base + threadIdx.x; i < end; i += blockDim.x)
    atomicAdd(&h[dst[i] >> shift], 1);
  __syncthreads();
  if (threadIdx.x < NB) histG[threadIdx.x * nblk + blockIdx.x] = h[threadIdx.x];
}

// ==== Phase C: bin (dst,src) pairs into bucket-contiguous regions (LDS cursors) ====
__global__ void __launch_bounds__(256) k_binpairs(const int* __restrict__ src,
                                                  const int* __restrict__ dst, int E,
                                                  int nblk, int shift,
                                                  const int* __restrict__ histOff,
                                                  u64* __restrict__ pairs) {
  __shared__ int cur[NB];
  if (threadIdx.x < NB) cur[threadIdx.x] = histOff[threadIdx.x * nblk + blockIdx.x];
  __syncthreads();
  int base = blockIdx.x * CHUNK;
  int end = base + CHUNK < E ? base + CHUNK : E;
  for (int i = base + threadIdx.x; i < end; i += blockDim.x) {
    int d = dst[i];
    int s = src[i];
    int pos = atomicAdd(&cur[d >> shift], 1);
    pairs[pos] = ((u64)(unsigned)d << 32) | (unsigned)s;
  }
}

// ---- degree count over sorted pairs (localized atomics) ----
__global__ void __launch_bounds__(256) k_degp(const u64* __restrict__ pairs, int E,
                                              int* __restrict__ cnt) {
  int i = blockIdx.x * blockDim.x + threadIdx.x;
  if (i < E) atomicAdd(&cnt[(int)(pairs[i] >> 32)], 1);
}

// ---- final CSR scatter over sorted pairs (localized writes) ----
__global__ void __launch_bounds__(256) k_scatter2(const u64* __restrict__ pairs, int E,
                                                  int* __restrict__ cur,
                                                  int* __restrict__ csr) {
  int i = blockIdx.x * blockDim.x + threadIdx.x;
  if (i >= E) return;
  u64 p = pairs[i];
  int d = (int)(p >> 32);
  int pos = atomicAdd(&cur[d], 1);
  csr[pos] = (int)(unsigned)p;
}

// ---- dinv = rsqrt(deg+1) ----
__global__ void __launch_bounds__(256) k_dinv(const int* __restrict__ cnt, int N,
                                              float* __restrict__ dinv) {
  int i = blockIdx.x * blockDim.x + threadIdx.x;
  if (i < N) dinv[i] = rsqrtf((float)cnt[i] + 1.0f);
}

// ==== exclusive scan (in-place capable): cnt -> off, per-2048 block sums -> bsum ====
__global__ void __launch_bounds__(256) k_scan1(const int* __restrict__ cnt, int N,
                                               int* __restrict__ off, int* __restrict__ bsum) {
  __shared__ int lds[256];
  int base = blockIdx.x * 2048 + threadIdx.x * 8;
  int v[8];
  int s = 0;
  #pragma unroll
  for (int k = 0; k < 8; k++) {
    int i = base + k;
    v[k] = (i < N) ? cnt[i] : 0;
    s += v[k];
  }
  lds[threadIdx.x] = s;
  __syncthreads();
  for (int o = 1; o < 256; o <<= 1) {
    int t2 = (threadIdx.x >= o) ? lds[threadIdx.x - o] : 0;
    __syncthreads();
    lds[threadIdx.x] += t2;
    __syncthreads();
  }
  int run = lds[threadIdx.x] - s;
  #pragma unroll
  for (int k = 0; k < 8; k++) {
    int i = base + k;
    if (i < N) off[i] = run;
    run += v[k];
  }
  if (threadIdx.x == 255) bsum[blockIdx.x] = lds[255];
}

__global__ void __launch_bounds__(256) k_scan2(int* __restrict__ bsum, int nb) {
  __shared__ int lds[256];
  int base = threadIdx.x * 8;
  int v[8];
  int s = 0;
  #pragma unroll
  for (int k = 0; k < 8; k++) {
    int i = base + k;
    v[k] = (i < nb) ? bsum[i] : 0;
    s += v[k];
  }
  lds[threadIdx.x] = s;
  __syncthreads();
  for (int o = 1; o < 256; o <<= 1) {
    int t2 = (threadIdx.x >= o) ? lds[threadIdx.x - o] : 0;
    __syncthreads();
    lds[threadIdx.x] += t2;
    __syncthreads();
  }
  int run = lds[threadIdx.x] - s;
  #pragma unroll
  for (int k = 0; k < 8; k++) {
    int i = base + k;
    if (i < nb) bsum[i] = run;
    run += v[k];
  }
}

// off[i] += bsum[i/2048]; cur[i] = off[i]  (cur may alias off)
__global__ void __launch_bounds__(256) k_scan3(int* __restrict__ off,
                                               const int* __restrict__ bsum, int N,
                                               int* __restrict__ cur) {
  int i = blockIdx.x * blockDim.x + threadIdx.x;
  if (i >= N) return;
  int o = off[i] + bsum[i >> 11];
  off[i] = o;
  cur[i] = o;
}

// ---- layer-1 gather (F=1), h0 = x*a+b on the fly; self-loop folded in ----
__global__ void __launch_bounds__(256) k_gather1(const int* __restrict__ off,
                                                 const int* __restrict__ csr,
                                                 const float* __restrict__ x,
                                                 const float* __restrict__ dinv,
                                                 const float* __restrict__ ab0, int N, int E,
                                                 float* __restrict__ agg) {
  int d = blockIdx.x * blockDim.x + threadIdx.x;
  if (d >= N) return;
  float a = ab0[0], bb = ab0[1];
  int beg = off[d];
  int end = (d + 1 < N) ? off[d + 1] : E;
  float dv = dinv[d];
  float acc = fmaf(x[d], a, bb) * dv * dv;
  for (int e = beg; e < end; e++) {
    int s = csr[e];
    acc = fmaf(dinv[s] * dv, fmaf(x[s], a, bb), acc);
  }
  agg[d] = acc;
}

// ---- generic gather: thread = (node, float4 quad); self-loop folded in ----
template<int F>
__global__ void __launch_bounds__(256) k_gather(const int* __restrict__ off,
                                                const int* __restrict__ csr,
                                                const float* __restrict__ h,
                                                const float* __restrict__ dinv, int N, int E,
                                                float* __restrict__ agg) {
  constexpr int Q = F / 4;
  constexpr int SH = (Q == 2) ? 1 : 2;
  int t = blockIdx.x * blockDim.x + threadIdx.x;
  int d = t >> SH;
  if (d >= N) return;
  int q = t & (Q - 1);
  int beg = off[d];
  int end = (d + 1 < N) ? off[d + 1] : E;
  float dv = dinv[d];
  const float4* hp = (const float4*)h;
  float4 acc = hp[(size_t)d * Q + q];
  float c0 = dv * dv;
  acc.x *= c0; acc.y *= c0; acc.z *= c0; acc.w *= c0;
  for (int e = beg; e < end; e++) {
    int s = csr[e];
    float c = dinv[s] * dv;
    float4 v = hp[(size_t)s * Q + q];
    acc.x = fmaf(c, v.x, acc.x);
    acc.y = fmaf(c, v.y, acc.y);
    acc.z = fmaf(c, v.z, acc.z);
    acc.w = fmaf(c, v.w, acc.w);
  }
  ((float4*)agg)[(size_t)d * Q + q] = acc;
}

// ==== per-channel stats of y = gW + b, channel-group split (8 channels/block) ====
#define STATS_STEP(GK, K)                                   \
  {                                                         \
    const float gk_ = (GK);                                 \
    const float* wr_ = Wsh + (K) * 8;                       \
    y0.x = fmaf(gk_, wr_[0], y0.x);                         \
    y0.y = fmaf(gk_, wr_[1], y0.y);                         \
    y0.z = fmaf(gk_, wr_[2], y0.z);                         \
    y0.w = fmaf(gk_, wr_[3], y0.w);                         \
    y1.x = fmaf(gk_, wr_[4], y1.x);                         \
    y1.y = fmaf(gk_, wr_[5], y1.y);                         \
    y1.z = fmaf(gk_, wr_[6], y1.z);                         \
    y1.w = fmaf(gk_, wr_[7], y1.w);                         \
  }

template<int FI, int FO>
__global__ void __launch_bounds__(256) k_stats8(const float* __restrict__ g,
                                                const float* __restrict__ W,
                                                const float* __restrict__ b, int N,
                                                float* __restrict__ sums) {
  const int j0 = blockIdx.y * 8;
  __shared__ float Wsh[FI * 8];
  __shared__ float bsh[8];
  __shared__ float red[4][16];
  for (int t = threadIdx.x; t < FI * 8; t += blockDim.x) {
    int k = t >> 3, jj = t & 7;
    Wsh[t] = W[k * FO + j0 + jj];
  }
  if (threadIdx.x < 8) bsh[threadIdx.x] = b[j0 + threadIdx.x];
  __syncthreads();

  float4 s0 = {0.f, 0.f, 0.f, 0.f}, s1 = {0.f, 0.f, 0.f, 0.f};
  float4 q0 = {0.f, 0.f, 0.f, 0.f}, q1 = {0.f, 0.f, 0.f, 0.f};

  for (int i = blockIdx.x * blockDim.x + threadIdx.x; i < N; i += gridDim.x * blockDim.x) {
    float4 y0 = {bsh[0], bsh[1], bsh[2], bsh[3]};
    float4 y1 = {bsh[4], bsh[5], bsh[6], bsh[7]};
    const float* gp = g + (size_t)i * FI;
    if constexpr (FI == 1) {
      STATS_STEP(gp[0], 0)
    } else if constexpr (FI == 8) {
      float4 ga = *(const float4*)gp;
      float4 gb = *(const float4*)(gp + 4);
      STATS_STEP(ga.x, 0) STATS_STEP(ga.y, 1) STATS_STEP(ga.z, 2) STATS_STEP(ga.w, 3)
      STATS_STEP(gb.x, 4) STATS_STEP(gb.y, 5) STATS_STEP(gb.z, 6) STATS_STEP(gb.w, 7)
    } else {
      float4 ga = *(const float4*)gp;
      float4 gb = *(const float4*)(gp + 4);
      float4 gc = *(const float4*)(gp + 8);
      float4 gd = *(const float4*)(gp + 12);
      STATS_STEP(ga.x, 0)  STATS_STEP(ga.y, 1)  STATS_STEP(ga.z, 2)  STATS_STEP(ga.w, 3)
      STATS_STEP(gb.x, 4)  STATS_STEP(gb.y, 5)  STATS_STEP(gb.z, 6)  STATS_STEP(gb.w, 7)
      STATS_STEP(gc.x, 8)  STATS_STEP(gc.y, 9)  STATS_STEP(gc.z, 10) STATS_STEP(gc.w, 11)
      STATS_STEP(gd.x, 12) STATS_STEP(gd.y, 13) STATS_STEP(gd.z, 14) STATS_STEP(gd.w, 15)
    }
    s0.x += y0.x; s0.y += y0.y; s0.z += y0.z; s0.w += y0.w;
    s1.x += y1.x; s1.y += y1.y; s1.z += y1.z; s1.w += y1.w;
    q0.x = fmaf(y0.x, y0.x, q0.x); q0.y = fmaf(y0.y, y0.y, q0.y);
    q0.z = fmaf(y0.z, y0.z, q0.z); q0.w = fmaf(y0.w, y0.w, q0.w);
    q1.x = fmaf(y1.x, y1.x, q1.x); q1.y = fmaf(y1.y, y1.y, q1.y);
    q1.z = fmaf(y1.z, y1.z, q1.z); q1.w = fmaf(y1.w, y1.w, q1.w);
  }

  float vals[16] = {s0.x, s0.y, s0.z, s0.w, s1.x, s1.y, s1.z, s1.w,
                    q0.x, q0.y, q0.z, q0.w, q1.x, q1.y, q1.z, q1.w};
  #pragma unroll
  for (int c = 0; c < 16; c++) vals[c] = wave_sum(vals[c]);

  int wid = threadIdx.x >> 6, lane = threadIdx.x & 63;
  if (lane == 0) {
    #pragma unroll
    for (int c = 0; c < 16; c++) red[wid][c] = vals[c];
  }
  __syncthreads();
  if (threadIdx.x < 16) {
    int c = threadIdx.x;
    float t = red[0][c] + red[1][c] + red[2][c] + red[3][c];
    int j = j0 + (c & 7);
    atomic_add_f((c < 8) ? &sums[j] : &sums[FO + j], t);
  }
}

// ---- fold BN into per-channel affine ----
template<int FO>
__global__ void __launch_bounds__(64) k_affine(const float* __restrict__ sums,
                                               const float* __restrict__ gamma,
                                               const float* __restrict__ beta, float invN,
                                               float* __restrict__ ab) {
  int j = threadIdx.x;
  if (j >= FO) return;
  float mu = sums[j] * invN;
  float var = fmaf(-mu, mu, sums[FO + j] * invN);
  float r = rsqrtf(var + EPS);
  float a = gamma[j] * r;
  ab[j] = a;
  ab[FO + j] = beta[j] - mu * a;
}

// ---- transform: h = relu((gW+b)*alpha+delta) ----
template<int FI, int FO>
__global__ void __launch_bounds__(256) k_transform(const float* __restrict__ g,
                                                   const float* __restrict__ W,
                                                   const float* __restrict__ b,
                                                   const float* __restrict__ ab, int N,
                                                   float* __restrict__ h) {
  __shared__ float Ws[FI * FO];
  __shared__ float bs[FO];
  __shared__ float as2[2 * FO];
  for (int t = threadIdx.x; t < FI * FO; t += blockDim.x) Ws[t] = W[t];
  for (int t = threadIdx.x; t < FO; t += blockDim.x) bs[t] = b[t];
  for (int t = threadIdx.x; t < 2 * FO; t += blockDim.x) as2[t] = ab[t];
  __syncthreads();

  int i = blockIdx.x * blockDim.x + threadIdx.x;
  if (i >= N) return;

  float gv[FI];
  if constexpr (FI % 4 == 0) {
    const float4* g4 = (const float4*)(g + (size_t)i * FI);
    #pragma unroll
    for (int k = 0; k < FI / 4; k++) {
      float4 v = g4[k];
      gv[4 * k] = v.x; gv[4 * k + 1] = v.y; gv[4 * k + 2] = v.z; gv[4 * k + 3] = v.w;
    }
  } else {
    #pragma unroll
    for (int k = 0; k < FI; k++) gv[k] = g[(size_t)i * FI + k];
  }

  #pragma unroll
  for (int jq = 0; jq < FO / 4; jq++) {
    float4 y = {bs[4 * jq], bs[4 * jq + 1], bs[4 * jq + 2], bs[4 * jq + 3]};
    #pragma unroll
    for (int k = 0; k < FI; k++) {
      float gk = gv[k];
      const float* wr = Ws + k * FO + 4 * jq;
      y.x = fmaf(gk, wr[0], y.x);
      y.y = fmaf(gk, wr[1], y.y);
      y.z = fmaf(gk, wr[2], y.z);
      y.w = fmaf(gk, wr[3], y.w);
    }
    float4 o;
    o.x = fmaxf(fmaf(y.x, as2[4 * jq + 0], as2[FO + 4 * jq + 0]), 0.f);
    o.y = fmaxf(fmaf(y.y, as2[4 * jq + 1], as2[FO + 4 * jq + 1]), 0.f);
    o.z = fmaxf(fmaf(y.z, as2[4 * jq + 2], as2[FO + 4 * jq + 2]), 0.f);
    o.w = fmaxf(fmaf(y.w, as2[4 * jq + 3], as2[FO + 4 * jq + 3]), 0.f);
    ((float4*)(h + (size_t)i * FO))[jq] = o;
  }
}

// ---- layer-3 transform fused with segment-max pooling ----
template<int FI, int FO>
__global__ void __launch_bounds__(256) k_pool(const float* __restrict__ g,
                                              const float* __restrict__ W,
                                              const float* __restrict__ b,
                                              const float* __restrict__ ab,
                                              const int* __restrict__ batch, int N, int B,
                                              unsigned* __restrict__ pooled) {
  __shared__ float Ws[FI * FO];
  __shared__ float bs[FO];
  __shared__ float as2[2 * FO];
  __shared__ unsigned lpool[4 * FO];
  __shared__ int gid0s;
  for (int t = threadIdx.x; t < FI * FO; t += blockDim.x) Ws[t] = W[t];
  for (int t = threadIdx.x; t < FO; t += blockDim.x) bs[t] = b[t];
  for (int t = threadIdx.x; t < 2 * FO; t += blockDim.x) as2[t] = ab[t];
  if (threadIdx.x < 4 * FO) lpool[threadIdx.x] = 0u;
  int i0 = blockIdx.x * blockDim.x;
  if (threadIdx.x == 0) gid0s = batch[i0 < N ? i0 : (N - 1)];
  __syncthreads();
  int gid0 = gid0s;

  int i = i0 + threadIdx.x;
  if (i < N) {
    float gv[FI];
    const float4* g4 = (const float4*)(g + (size_t)i * FI);
    #pragma unroll
    for (int k = 0; k < FI / 4; k++) {
      float4 v = g4[k];
      gv[4 * k] = v.x; gv[4 * k + 1] = v.y; gv[4 * k + 2] = v.z; gv[4 * k + 3] = v.w;
    }
    int gid = batch[i];
    int slot = gid - gid0;
    #pragma unroll
    for (int j = 0; j < FO; j++) {
      float y = bs[j];
      #pragma unroll
      for (int k = 0; k < FI; k++) y = fmaf(gv[k], Ws[k * FO + j], y);
      float hv = fmaxf(fmaf(y, as2[j], as2[FO + j]), 0.f);
      unsigned u = __float_as_uint(hv);
      if (slot >= 0 && slot < 4) atomicMax(&lpool[slot * FO + j], u);
      else atomicMax(&pooled[(size_t)gid * FO + j], u);
    }
  }
  __syncthreads();
  for (int t = threadIdx.x; t < 4 * FO; t += blockDim.x) {
    unsigned v = lpool[t];
    int gid = gid0 + t / FO;
    if (v && gid < B) atomicMax(&pooled[(size_t)gid * FO + (t % FO)], v);
  }
}

// ---- final MLP ----
__global__ void __launch_bounds__(256) k_mlp(const unsigned* __restrict__ pooled,
                                             const float* __restrict__ W1,
                                             const float* __restrict__ b1,
                                             const float* __restrict__ W2,
                                             const float* __restrict__ b2, int B,
                                             float* __restrict__ out) {
  int gidx = blockIdx.x * blockDim.x + threadIdx.x;
  if (gidx >= B) return;
  float p[32];
  #pragma unroll
  for (int k = 0; k < 32; k++) p[k] = __uint_as_float(pooled[gidx * 32 + k]);
  float o0 = b2[0], o1 = b2[1];
  for (int j = 0; j < 64; j++) {
    float y = b1[j];
    #pragma unroll
    for (int k = 0; k < 32; k++) y = fmaf(p[k], W1[k * 64 + j], y);
    y = fmaxf(y, 0.f);
    o0 = fmaf(y, W2[j * 2 + 0], o0);
    o1 = fmaf(y, W2[j * 2 + 1], o1);
  }
  out[gidx * 2 + 0] = fmaxf(o0, 0.f);
  out[gidx * 2 + 1] = fmaxf(o1, 0.f);
}

extern "C" void kernel_launch(void* const* d_in, const int* in_sizes, int n_in,
                              void* d_out, int out_size, void* d_ws, size_t ws_size,
                              hipStream_t stream) {
  const float* x     = (const float*)d_in[0];
  const int*   ei    = (const int*)d_in[1];
  const int*   batch = (const int*)d_in[2];
  const float* bn0_g = (const float*)d_in[3];
  const float* bn0_b = (const float*)d_in[4];
  const float* W1    = (const float*)d_in[5];
  const float* b1    = (const float*)d_in[6];
  const float* bn1_g = (const float*)d_in[7];
  const float* bn1_b = (const float*)d_in[8];
  const float* W2    = (const float*)d_in[9];
  const float* b2    = (const float*)d_in[10];
  const float* bn2_g = (const float*)d_in[11];
  const float* bn2_b = (const float*)d_in[12];
  const float* W3    = (const float*)d_in[13];
  const float* b3    = (const float*)d_in[14];
  const float* bn3_g = (const float*)d_in[15];
  const float* bn3_b = (const float*)d_in[16];
  const float* L1W   = (const float*)d_in[17];
  const float* L1b   = (const float*)d_in[18];
  const float* L2W   = (const float*)d_in[19];
  const float* L2b   = (const float*)d_in[20];

  const int N = in_sizes[0];
  const int E = in_sizes[1] / 2;
  const int B = out_size / 2;
  const int* src = ei;
  const int* dst = ei + E;
  const float invN = 1.0f / (float)N;

  // bucket shift: ceil(N / 2^shift) <= NB
  int shift = 0;
  while (((N - 1) >> shift) >= NB) shift++;
  const int nblk = (E + CHUNK - 1) / CHUNK;
  const int M = NB * nblk;  // hist entries

  char* ws = (char*)d_ws;
  size_t off_b = 0;
  auto alloc = [&](size_t bytes) {
    char* p = ws + off_b;
    off_b += (bytes + 255) & ~(size_t)255;
    return p;
  };
  auto al = [](size_t b) { return (b + 255) & ~(size_t)255; };

  int*      cnt    = (int*)alloc((size_t)N * 4);   // also cursor after scan3
  int*      offv   = (int*)alloc((size_t)N * 4);
  float*    dinv   = (float*)alloc((size_t)N * 4);
  int*      bsum   = (int*)alloc(4096 * 4);
  int*      histG  = (int*)alloc((size_t)M * 4);
  int*      csr    = (int*)alloc((size_t)E * 4);

  // big region: during CSR build holds pairs (E*8); during layers holds
  // {agg1 + h1 + agg2 | agg3} followed by h2.
  size_t szR = al((size_t)N * 4) + al((size_t)N * 8 * 4) + al((size_t)N * 8 * 4);
  if (szR < (size_t)N * 16 * 4) szR = (size_t)N * 16 * 4;
  szR = al(szR);
  size_t szH2 = al((size_t)N * 16 * 4);
  size_t szBig = szR + szH2;
  if (szBig < (size_t)E * 8) szBig = (size_t)E * 8;
  char* bigbuf = alloc(szBig);
  u64*   pairs = (u64*)bigbuf;
  float* agg1  = (float*)bigbuf;
  float* h1    = (float*)(bigbuf + al((size_t)N * 4));
  float* agg2  = (float*)(bigbuf + al((size_t)N * 4) + al((size_t)N * 8 * 4));
  float* agg3  = (float*)bigbuf;
  float* h2    = (float*)(bigbuf + szR);

  unsigned* pooled = (unsigned*)alloc((size_t)B * 32 * 4);
  float*    stats  = (float*)alloc(1024 * 4);

  float* sums0 = stats + 0;
  float* ab0   = stats + 4;
  float* sums1 = stats + 8;
  float* ab1   = stats + 24;
  float* sums2 = stats + 40;
  float* ab2   = stats + 72;
  float* sums3 = stats + 104;
  float* ab3   = stats + 168;

  int* cur = cnt;  // alias: cnt dead after scan1

  hipMemsetAsync(cnt, 0, (size_t)N * 4, stream);
  hipMemsetAsync(stats, 0, 1024 * 4, stream);
  hipMemsetAsync(pooled, 0, (size_t)B * 32 * 4, stream);

  const int T = 256;
  const int gN = (N + T - 1) / T;
  const int gE = (E + T - 1) / T;
  const int gS = 1024;
  const int gX = 512;
  const int nbScanN = (N + 2047) / 2048;
  const int nbScanM = (M + 2047) / 2048;

  // bn0 (independent of edges)
  k_s0<<<gS, T, 0, stream>>>(x, N, sums0);
  k_c0<<<1, 1, 0, stream>>>(sums0, bn0_g, bn0_b, invN, ab0);

  // ==== CSR build: bucket-sort pairs, then localized deg + scatter ====
  k_hist<<<nblk, T, 0, stream>>>(dst, E, nblk, shift, histG);
  k_scan1<<<nbScanM, T, 0, stream>>>(histG, M, histG, bsum);          // in-place
  k_scan2<<<1, T, 0, stream>>>(bsum, nbScanM);
  k_scan3<<<(M + T - 1) / T, T, 0, stream>>>(histG, bsum, M, histG);  // fixup in-place
  k_binpairs<<<nblk, T, 0, stream>>>(src, dst, E, nblk, shift, histG, pairs);
  k_degp<<<gE, T, 0, stream>>>(pairs, E, cnt);
  k_dinv<<<gN, T, 0, stream>>>(cnt, N, dinv);
  k_scan1<<<nbScanN, T, 0, stream>>>(cnt, N, offv, bsum);
  k_scan2<<<1, T, 0, stream>>>(bsum, nbScanN);
  k_scan3<<<gN, T, 0, stream>>>(offv, bsum, N, cur);
  k_scatter2<<<gE, T, 0, stream>>>(pairs, E, cur, csr);
  // pairs dead from here; bigbuf reused for layer buffers

  // layer 1 (FI=1 -> FO=8)
  k_gather1<<<gN, T, 0, stream>>>(offv, csr, x, dinv, ab0, N, E, agg1);
  k_stats8<1, 8><<<dim3(gX, 1), T, 0, stream>>>(agg1, W1, b1, N, sums1);
  k_affine<8><<<1, 64, 0, stream>>>(sums1, bn1_g, bn1_b, invN, ab1);
  k_transform<1, 8><<<gN, T, 0, stream>>>(agg1, W1, b1, ab1, N, h1);

  // layer 2 (FI=8 -> FO=16)
  k_gather<8><<<(N * 2 + T - 1) / T, T, 0, stream>>>(offv, csr, h1, dinv, N, E, agg2);
  k_stats8<8, 16><<<dim3(gX, 2), T, 0, stream>>>(agg2, W2, b2, N, sums2);
  k_affine<16><<<1, 64, 0, stream>>>(sums2, bn2_g, bn2_b, invN, ab2);
  k_transform<8, 16><<<gN, T, 0, stream>>>(agg2, W2, b2, ab2, N, h2);

  // layer 3 (FI=16 -> FO=32); agg3 aliases dead agg1/h1/agg2
  k_gather<16><<<(N * 4 + T - 1) / T, T, 0, stream>>>(offv, csr, h2, dinv, N, E, agg3);
  k_stats8<16, 32><<<dim3(gX, 4), T, 0, stream>>>(agg3, W3, b3, N, sums3);
  k_affine<32><<<1, 64, 0, stream>>>(sums3, bn3_g, bn3_b, invN, ab3);
  k_pool<16, 32><<<gN, T, 0, stream>>>(agg3, W3, b3, ab3, batch, N, B, pooled);

  // final MLP
  k_mlp<<<(B + T - 1) / T, T, 0, stream>>>(pooled, L1W, L1b, L2W, L2b, B, (float*)d_out);
}

// Round 6
// 1110.809 us; speedup vs baseline: 5.8520x; 1.5049x over previous
//
#include <hip/hip_runtime.h>

#define EPS 1e-5f
#define CHUNK 16384
#define MAXB 512            // max buckets (LDS arrays in hist/binpairs)
#define BSH 10              // nodes per bucket = 1024
#define BNODES (1 << BSH)

typedef unsigned long long u64;

__device__ __forceinline__ float wave_sum(float v) {
  #pragma unroll
  for (int o = 32; o > 0; o >>= 1) v += __shfl_down(v, o, 64);
  return v;
}

__device__ __forceinline__ void atomic_add_f(float* p, float v) {
  unsafeAtomicAdd(p, v);
}

// ---- bn0 stats: sum, sumsq of x ----
__global__ void __launch_bounds__(256) k_s0(const float* __restrict__ x, int N,
                                            float* __restrict__ sums) {
  float s = 0.f, q = 0.f;
  for (int i = blockIdx.x * blockDim.x + threadIdx.x; i < N; i += gridDim.x * blockDim.x) {
    float v = x[i];
    s += v;
    q = fmaf(v, v, q);
  }
  s = wave_sum(s);
  q = wave_sum(q);
  if ((threadIdx.x & 63) == 0) { atomic_add_f(&sums[0], s); atomic_add_f(&sums[1], q); }
}

// ---- bn0 affine ----
__global__ void __launch_bounds__(64) k_c0(const float* __restrict__ sums,
                                           const float* __restrict__ g,
                                           const float* __restrict__ b, float invN,
                                           float* __restrict__ ab) {
  float mu = sums[0] * invN;
  float var = fmaf(-mu, mu, sums[1] * invN);
  float r = rsqrtf(var + EPS);
  float a = g[0] * r;
  ab[0] = a;
  ab[1] = b[0] - mu * a;
}

// ==== Phase A: per-chunk bucket histogram (bucket = dst >> BSH) ====
__global__ void __launch_bounds__(256) k_hist(const int* __restrict__ dst, int E, int nblk,
                                              int nbk, int* __restrict__ histG) {
  __shared__ int h[MAXB];
  for (int t = threadIdx.x; t < nbk; t += blockDim.x) h[t] = 0;
  __syncthreads();
  int base = blockIdx.x * CHUNK;
  int end = base + CHUNK < E ? base + CHUNK : E;
  for (int i = base + threadIdx.x; i < end; i += blockDim.x)
    atomicAdd(&h[dst[i] >> BSH], 1);
  __syncthreads();
  for (int t = threadIdx.x; t < nbk; t += blockDim.x)
    histG[t * nblk + blockIdx.x] = h[t];
}

// ==== Phase C: bin (dst,src) pairs into bucket-contiguous regions (LDS cursors) ====
__global__ void __launch_bounds__(256) k_binpairs(const int* __restrict__ src,
                                                  const int* __restrict__ dst, int E,
                                                  int nblk, int nbk,
                                                  const int* __restrict__ histOff,
                                                  u64* __restrict__ pairs) {
  __shared__ int cur[MAXB];
  for (int t = threadIdx.x; t < nbk; t += blockDim.x)
    cur[t] = histOff[t * nblk + blockIdx.x];
  __syncthreads();
  int base = blockIdx.x * CHUNK;
  int end = base + CHUNK < E ? base + CHUNK : E;
  for (int i = base + threadIdx.x; i < end; i += blockDim.x) {
    int d = dst[i];
    int s = src[i];
    int pos = atomicAdd(&cur[d >> BSH], 1);
    pairs[pos] = ((u64)(unsigned)d << 32) | (unsigned)s;
  }
}

// ==== fused per-bucket: degree -> dinv/offv (global prefix = bucket base) -> csr ====
// one block per bucket; all writes land in block-exclusive dense regions.
__global__ void __launch_bounds__(256) k_bucket_csr(const u64* __restrict__ pairs,
                                                    const int* __restrict__ histG,
                                                    int nblk, int nbk, int E, int N,
                                                    int* __restrict__ offv,
                                                    float* __restrict__ dinv,
                                                    int* __restrict__ csr) {
  __shared__ int cnt[BNODES];
  __shared__ int sscan[256];
  int b = blockIdx.x;
  int d0 = b << BSH;
  #pragma unroll
  for (int k = 0; k < BNODES / 256; k++) cnt[threadIdx.x + 256 * k] = 0;
  int beg = histG[(size_t)b * nblk];
  int end = (b + 1 < nbk) ? histG[(size_t)(b + 1) * nblk] : E;
  __syncthreads();

  // 1) per-node degree histogram
  for (int i = beg + threadIdx.x; i < end; i += 256)
    atomicAdd(&cnt[(int)(pairs[i] >> 32) - d0], 1);
  __syncthreads();

  // 2) block exclusive scan over BNODES entries (4 per thread)
  int base4 = threadIdx.x * 4;
  int v0 = cnt[base4], v1 = cnt[base4 + 1], v2 = cnt[base4 + 2], v3 = cnt[base4 + 3];
  int s = v0 + v1 + v2 + v3;
  sscan[threadIdx.x] = s;
  __syncthreads();
  for (int o = 1; o < 256; o <<= 1) {
    int t2 = (threadIdx.x >= o) ? sscan[threadIdx.x - o] : 0;
    __syncthreads();
    sscan[threadIdx.x] += t2;
    __syncthreads();
  }
  int run = sscan[threadIdx.x] - s;  // exclusive

  // 3) write offv/dinv densely; leave cursors (local exclusive offsets) in cnt
  {
    int i = d0 + base4;
    if (i < N)     { offv[i] = beg + run;     dinv[i] = rsqrtf((float)v0 + 1.f); }
    cnt[base4] = run; run += v0;
    if (i + 1 < N) { offv[i + 1] = beg + run; dinv[i + 1] = rsqrtf((float)v1 + 1.f); }
    cnt[base4 + 1] = run; run += v1;
    if (i + 2 < N) { offv[i + 2] = beg + run; dinv[i + 2] = rsqrtf((float)v2 + 1.f); }
    cnt[base4 + 2] = run; run += v2;
    if (i + 3 < N) { offv[i + 3] = beg + run; dinv[i + 3] = rsqrtf((float)v3 + 1.f); }
    cnt[base4 + 3] = run; run += v3;
  }
  __syncthreads();

  // 4) scatter srcs into this bucket's dense csr region
  for (int i = beg + threadIdx.x; i < end; i += 256) {
    u64 p = pairs[i];
    int d = (int)(p >> 32);
    int pos = beg + atomicAdd(&cnt[d - d0], 1);
    csr[pos] = (int)(unsigned)p;
  }
}

// ==== exclusive scan kernels (used for histG only) ====
__global__ void __launch_bounds__(256) k_scan1(const int* __restrict__ cnt, int N,
                                               int* __restrict__ off, int* __restrict__ bsum) {
  __shared__ int lds[256];
  int base = blockIdx.x * 2048 + threadIdx.x * 8;
  int v[8];
  int s = 0;
  #pragma unroll
  for (int k = 0; k < 8; k++) {
    int i = base + k;
    v[k] = (i < N) ? cnt[i] : 0;
    s += v[k];
  }
  lds[threadIdx.x] = s;
  __syncthreads();
  for (int o = 1; o < 256; o <<= 1) {
    int t2 = (threadIdx.x >= o) ? lds[threadIdx.x - o] : 0;
    __syncthreads();
    lds[threadIdx.x] += t2;
    __syncthreads();
  }
  int run = lds[threadIdx.x] - s;
  #pragma unroll
  for (int k = 0; k < 8; k++) {
    int i = base + k;
    if (i < N) off[i] = run;
    run += v[k];
  }
  if (threadIdx.x == 255) bsum[blockIdx.x] = lds[255];
}

__global__ void __launch_bounds__(256) k_scan2(int* __restrict__ bsum, int nb) {
  __shared__ int lds[256];
  int base = threadIdx.x * 8;
  int v[8];
  int s = 0;
  #pragma unroll
  for (int k = 0; k < 8; k++) {
    int i = base + k;
    v[k] = (i < nb) ? bsum[i] : 0;
    s += v[k];
  }
  lds[threadIdx.x] = s;
  __syncthreads();
  for (int o = 1; o < 256; o <<= 1) {
    int t2 = (threadIdx.x >= o) ? lds[threadIdx.x - o] : 0;
    __syncthreads();
    lds[threadIdx.x] += t2;
    __syncthreads();
  }
  int run = lds[threadIdx.x] - s;
  #pragma unroll
  for (int k = 0; k < 8; k++) {
    int i = base + k;
    if (i < nb) bsum[i] = run;
    run += v[k];
  }
}

__global__ void __launch_bounds__(256) k_scan3(int* __restrict__ off,
                                               const int* __restrict__ bsum, int N) {
  int i = blockIdx.x * blockDim.x + threadIdx.x;
  if (i >= N) return;
  off[i] = off[i] + bsum[i >> 11];
}

// ---- layer-1 gather (F=1), h0 = x*a+b on the fly; self-loop folded in ----
__global__ void __launch_bounds__(256) k_gather1(const int* __restrict__ off,
                                                 const int* __restrict__ csr,
                                                 const float* __restrict__ x,
                                                 const float* __restrict__ dinv,
                                                 const float* __restrict__ ab0, int N, int E,
                                                 float* __restrict__ agg) {
  int d = blockIdx.x * blockDim.x + threadIdx.x;
  if (d >= N) return;
  float a = ab0[0], bb = ab0[1];
  int beg = off[d];
  int end = (d + 1 < N) ? off[d + 1] : E;
  float dv = dinv[d];
  float acc = fmaf(x[d], a, bb) * dv * dv;
  for (int e = beg; e < end; e++) {
    int s = csr[e];
    acc = fmaf(dinv[s] * dv, fmaf(x[s], a, bb), acc);
  }
  agg[d] = acc;
}

// ---- generic gather: thread = (node, float4 quad); self-loop folded in ----
template<int F>
__global__ void __launch_bounds__(256) k_gather(const int* __restrict__ off,
                                                const int* __restrict__ csr,
                                                const float* __restrict__ h,
                                                const float* __restrict__ dinv, int N, int E,
                                                float* __restrict__ agg) {
  constexpr int Q = F / 4;
  constexpr int SH = (Q == 2) ? 1 : 2;
  int t = blockIdx.x * blockDim.x + threadIdx.x;
  int d = t >> SH;
  if (d >= N) return;
  int q = t & (Q - 1);
  int beg = off[d];
  int end = (d + 1 < N) ? off[d + 1] : E;
  float dv = dinv[d];
  const float4* hp = (const float4*)h;
  float4 acc = hp[(size_t)d * Q + q];
  float c0 = dv * dv;
  acc.x *= c0; acc.y *= c0; acc.z *= c0; acc.w *= c0;
  for (int e = beg; e < end; e++) {
    int s = csr[e];
    float c = dinv[s] * dv;
    float4 v = hp[(size_t)s * Q + q];
    acc.x = fmaf(c, v.x, acc.x);
    acc.y = fmaf(c, v.y, acc.y);
    acc.z = fmaf(c, v.z, acc.z);
    acc.w = fmaf(c, v.w, acc.w);
  }
  ((float4*)agg)[(size_t)d * Q + q] = acc;
}

// ==== per-channel stats of y = gW + b, channel-group split (8 channels/block) ====
#define STATS_STEP(GK, K)                                   \
  {                                                         \
    const float gk_ = (GK);                                 \
    const float* wr_ = Wsh + (K) * 8;                       \
    y0.x = fmaf(gk_, wr_[0], y0.x);                         \
    y0.y = fmaf(gk_, wr_[1], y0.y);                         \
    y0.z = fmaf(gk_, wr_[2], y0.z);                         \
    y0.w = fmaf(gk_, wr_[3], y0.w);                         \
    y1.x = fmaf(gk_, wr_[4], y1.x);                         \
    y1.y = fmaf(gk_, wr_[5], y1.y);                         \
    y1.z = fmaf(gk_, wr_[6], y1.z);                         \
    y1.w = fmaf(gk_, wr_[7], y1.w);                         \
  }

template<int FI, int FO>
__global__ void __launch_bounds__(256) k_stats8(const float* __restrict__ g,
                                                const float* __restrict__ W,
                                                const float* __restrict__ b, int N,
                                                float* __restrict__ sums) {
  const int j0 = blockIdx.y * 8;
  __shared__ float Wsh[FI * 8];
  __shared__ float bsh[8];
  __shared__ float red[4][16];
  for (int t = threadIdx.x; t < FI * 8; t += blockDim.x) {
    int k = t >> 3, jj = t & 7;
    Wsh[t] = W[k * FO + j0 + jj];
  }
  if (threadIdx.x < 8) bsh[threadIdx.x] = b[j0 + threadIdx.x];
  __syncthreads();

  float4 s0 = {0.f, 0.f, 0.f, 0.f}, s1 = {0.f, 0.f, 0.f, 0.f};
  float4 q0 = {0.f, 0.f, 0.f, 0.f}, q1 = {0.f, 0.f, 0.f, 0.f};

  for (int i = blockIdx.x * blockDim.x + threadIdx.x; i < N; i += gridDim.x * blockDim.x) {
    float4 y0 = {bsh[0], bsh[1], bsh[2], bsh[3]};
    float4 y1 = {bsh[4], bsh[5], bsh[6], bsh[7]};
    const float* gp = g + (size_t)i * FI;
    if constexpr (FI == 1) {
      STATS_STEP(gp[0], 0)
    } else if constexpr (FI == 8) {
      float4 ga = *(const float4*)gp;
      float4 gb = *(const float4*)(gp + 4);
      STATS_STEP(ga.x, 0) STATS_STEP(ga.y, 1) STATS_STEP(ga.z, 2) STATS_STEP(ga.w, 3)
      STATS_STEP(gb.x, 4) STATS_STEP(gb.y, 5) STATS_STEP(gb.z, 6) STATS_STEP(gb.w, 7)
    } else {
      float4 ga = *(const float4*)gp;
      float4 gb = *(const float4*)(gp + 4);
      float4 gc = *(const float4*)(gp + 8);
      float4 gd = *(const float4*)(gp + 12);
      STATS_STEP(ga.x, 0)  STATS_STEP(ga.y, 1)  STATS_STEP(ga.z, 2)  STATS_STEP(ga.w, 3)
      STATS_STEP(gb.x, 4)  STATS_STEP(gb.y, 5)  STATS_STEP(gb.z, 6)  STATS_STEP(gb.w, 7)
      STATS_STEP(gc.x, 8)  STATS_STEP(gc.y, 9)  STATS_STEP(gc.z, 10) STATS_STEP(gc.w, 11)
      STATS_STEP(gd.x, 12) STATS_STEP(gd.y, 13) STATS_STEP(gd.z, 14) STATS_STEP(gd.w, 15)
    }
    s0.x += y0.x; s0.y += y0.y; s0.z += y0.z; s0.w += y0.w;
    s1.x += y1.x; s1.y += y1.y; s1.z += y1.z; s1.w += y1.w;
    q0.x = fmaf(y0.x, y0.x, q0.x); q0.y = fmaf(y0.y, y0.y, q0.y);
    q0.z = fmaf(y0.z, y0.z, q0.z); q0.w = fmaf(y0.w, y0.w, q0.w);
    q1.x = fmaf(y1.x, y1.x, q1.x); q1.y = fmaf(y1.y, y1.y, q1.y);
    q1.z = fmaf(y1.z, y1.z, q1.z); q1.w = fmaf(y1.w, y1.w, q1.w);
  }

  float vals[16] = {s0.x, s0.y, s0.z, s0.w, s1.x, s1.y, s1.z, s1.w,
                    q0.x, q0.y, q0.z, q0.w, q1.x, q1.y, q1.z, q1.w};
  #pragma unroll
  for (int c = 0; c < 16; c++) vals[c] = wave_sum(vals[c]);

  int wid = threadIdx.x >> 6, lane = threadIdx.x & 63;
  if (lane == 0) {
    #pragma unroll
    for (int c = 0; c < 16; c++) red[wid][c] = vals[c];
  }
  __syncthreads();
  if (threadIdx.x < 16) {
    int c = threadIdx.x;
    float t = red[0][c] + red[1][c] + red[2][c] + red[3][c];
    int j = j0 + (c & 7);
    atomic_add_f((c < 8) ? &sums[j] : &sums[FO + j], t);
  }
}

// ---- fold BN into per-channel affine ----
template<int FO>
__global__ void __launch_bounds__(64) k_affine(const float* __restrict__ sums,
                                               const float* __restrict__ gamma,
                                               const float* __restrict__ beta, float invN,
                                               float* __restrict__ ab) {
  int j = threadIdx.x;
  if (j >= FO) return;
  float mu = sums[j] * invN;
  float var = fmaf(-mu, mu, sums[FO + j] * invN);
  float r = rsqrtf(var + EPS);
  float a = gamma[j] * r;
  ab[j] = a;
  ab[FO + j] = beta[j] - mu * a;
}

// ---- transform: h = relu((gW+b)*alpha+delta) ----
template<int FI, int FO>
__global__ void __launch_bounds__(256) k_transform(const float* __restrict__ g,
                                                   const float* __restrict__ W,
                                                   const float* __restrict__ b,
                                                   const float* __restrict__ ab, int N,
                                                   float* __restrict__ h) {
  __shared__ float Ws[FI * FO];
  __shared__ float bs[FO];
  __shared__ float as2[2 * FO];
  for (int t = threadIdx.x; t < FI * FO; t += blockDim.x) Ws[t] = W[t];
  for (int t = threadIdx.x; t < FO; t += blockDim.x) bs[t] = b[t];
  for (int t = threadIdx.x; t < 2 * FO; t += blockDim.x) as2[t] = ab[t];
  __syncthreads();

  int i = blockIdx.x * blockDim.x + threadIdx.x;
  if (i >= N) return;

  float gv[FI];
  if constexpr (FI % 4 == 0) {
    const float4* g4 = (const float4*)(g + (size_t)i * FI);
    #pragma unroll
    for (int k = 0; k < FI / 4; k++) {
      float4 v = g4[k];
      gv[4 * k] = v.x; gv[4 * k + 1] = v.y; gv[4 * k + 2] = v.z; gv[4 * k + 3] = v.w;
    }
  } else {
    #pragma unroll
    for (int k = 0; k < FI; k++) gv[k] = g[(size_t)i * FI + k];
  }

  #pragma unroll
  for (int jq = 0; jq < FO / 4; jq++) {
    float4 y = {bs[4 * jq], bs[4 * jq + 1], bs[4 * jq + 2], bs[4 * jq + 3]};
    #pragma unroll
    for (int k = 0; k < FI; k++) {
      float gk = gv[k];
      const float* wr = Ws + k * FO + 4 * jq;
      y.x = fmaf(gk, wr[0], y.x);
      y.y = fmaf(gk, wr[1], y.y);
      y.z = fmaf(gk, wr[2], y.z);
      y.w = fmaf(gk, wr[3], y.w);
    }
    float4 o;
    o.x = fmaxf(fmaf(y.x, as2[4 * jq + 0], as2[FO + 4 * jq + 0]), 0.f);
    o.y = fmaxf(fmaf(y.y, as2[4 * jq + 1], as2[FO + 4 * jq + 1]), 0.f);
    o.z = fmaxf(fmaf(y.z, as2[4 * jq + 2], as2[FO + 4 * jq + 2]), 0.f);
    o.w = fmaxf(fmaf(y.w, as2[4 * jq + 3], as2[FO + 4 * jq + 3]), 0.f);
    ((float4*)(h + (size_t)i * FO))[jq] = o;
  }
}

// ---- layer-3 transform fused with segment-max pooling ----
template<int FI, int FO>
__global__ void __launch_bounds__(256) k_pool(const float* __restrict__ g,
                                              const float* __restrict__ W,
                                              const float* __restrict__ b,
                                              const float* __restrict__ ab,
                                              const int* __restrict__ batch, int N, int B,
                                              unsigned* __restrict__ pooled) {
  __shared__ float Ws[FI * FO];
  __shared__ float bs[FO];
  __shared__ float as2[2 * FO];
  __shared__ unsigned lpool[4 * FO];
  __shared__ int gid0s;
  for (int t = threadIdx.x; t < FI * FO; t += blockDim.x) Ws[t] = W[t];
  for (int t = threadIdx.x; t < FO; t += blockDim.x) bs[t] = b[t];
  for (int t = threadIdx.x; t < 2 * FO; t += blockDim.x) as2[t] = ab[t];
  if (threadIdx.x < 4 * FO) lpool[threadIdx.x] = 0u;
  int i0 = blockIdx.x * blockDim.x;
  if (threadIdx.x == 0) gid0s = batch[i0 < N ? i0 : (N - 1)];
  __syncthreads();
  int gid0 = gid0s;

  int i = i0 + threadIdx.x;
  if (i < N) {
    float gv[FI];
    const float4* g4 = (const float4*)(g + (size_t)i * FI);
    #pragma unroll
    for (int k = 0; k < FI / 4; k++) {
      float4 v = g4[k];
      gv[4 * k] = v.x; gv[4 * k + 1] = v.y; gv[4 * k + 2] = v.z; gv[4 * k + 3] = v.w;
    }
    int gid = batch[i];
    int slot = gid - gid0;
    #pragma unroll
    for (int j = 0; j < FO; j++) {
      float y = bs[j];
      #pragma unroll
      for (int k = 0; k < FI; k++) y = fmaf(gv[k], Ws[k * FO + j], y);
      float hv = fmaxf(fmaf(y, as2[j], as2[FO + j]), 0.f);
      unsigned u = __float_as_uint(hv);
      if (slot >= 0 && slot < 4) atomicMax(&lpool[slot * FO + j], u);
      else atomicMax(&pooled[(size_t)gid * FO + j], u);
    }
  }
  __syncthreads();
  for (int t = threadIdx.x; t < 4 * FO; t += blockDim.x) {
    unsigned v = lpool[t];
    int gid = gid0 + t / FO;
    if (v && gid < B) atomicMax(&pooled[(size_t)gid * FO + (t % FO)], v);
  }
}

// ---- final MLP ----
__global__ void __launch_bounds__(256) k_mlp(const unsigned* __restrict__ pooled,
                                             const float* __restrict__ W1,
                                             const float* __restrict__ b1,
                                             const float* __restrict__ W2,
                                             const float* __restrict__ b2, int B,
                                             float* __restrict__ out) {
  int gidx = blockIdx.x * blockDim.x + threadIdx.x;
  if (gidx >= B) return;
  float p[32];
  #pragma unroll
  for (int k = 0; k < 32; k++) p[k] = __uint_as_float(pooled[gidx * 32 + k]);
  float o0 = b2[0], o1 = b2[1];
  for (int j = 0; j < 64; j++) {
    float y = b1[j];
    #pragma unroll
    for (int k = 0; k < 32; k++) y = fmaf(p[k], W1[k * 64 + j], y);
    y = fmaxf(y, 0.f);
    o0 = fmaf(y, W2[j * 2 + 0], o0);
    o1 = fmaf(y, W2[j * 2 + 1], o1);
  }
  out[gidx * 2 + 0] = fmaxf(o0, 0.f);
  out[gidx * 2 + 1] = fmaxf(o1, 0.f);
}

extern "C" void kernel_launch(void* const* d_in, const int* in_sizes, int n_in,
                              void* d_out, int out_size, void* d_ws, size_t ws_size,
                              hipStream_t stream) {
  const float* x     = (const float*)d_in[0];
  const int*   ei    = (const int*)d_in[1];
  const int*   batch = (const int*)d_in[2];
  const float* bn0_g = (const float*)d_in[3];
  const float* bn0_b = (const float*)d_in[4];
  const float* W1    = (const float*)d_in[5];
  const float* b1    = (const float*)d_in[6];
  const float* bn1_g = (const float*)d_in[7];
  const float* bn1_b = (const float*)d_in[8];
  const float* W2    = (const float*)d_in[9];
  const float* b2    = (const float*)d_in[10];
  const float* bn2_g = (const float*)d_in[11];
  const float* bn2_b = (const float*)d_in[12];
  const float* W3    = (const float*)d_in[13];
  const float* b3    = (const float*)d_in[14];
  const float* bn3_g = (const float*)d_in[15];
  const float* bn3_b = (const float*)d_in[16];
  const float* L1W   = (const float*)d_in[17];
  const float* L1b   = (const float*)d_in[18];
  const float* L2W   = (const float*)d_in[19];
  const float* L2b   = (const float*)d_in[20];

  const int N = in_sizes[0];
  const int E = in_sizes[1] / 2;
  const int B = out_size / 2;
  const int* src = ei;
  const int* dst = ei + E;
  const float invN = 1.0f / (float)N;

  const int nbk = (N + BNODES - 1) >> BSH;  // buckets (<= MAXB for N <= 512K)
  const int nblk = (E + CHUNK - 1) / CHUNK;
  const int M = nbk * nblk;

  char* ws = (char*)d_ws;
  size_t off_b = 0;
  auto alloc = [&](size_t bytes) {
    char* p = ws + off_b;
    off_b += (bytes + 255) & ~(size_t)255;
    return p;
  };
  auto al = [](size_t b) { return (b + 255) & ~(size_t)255; };

  int*      offv   = (int*)alloc((size_t)N * 4);
  float*    dinv   = (float*)alloc((size_t)N * 4);
  int*      bsum   = (int*)alloc(4096 * 4);
  int*      histG  = (int*)alloc((size_t)M * 4);
  int*      csr    = (int*)alloc((size_t)E * 4);

  // big region: during CSR build holds pairs (E*8); during layers holds
  // {agg1 + h1 + agg2 | agg3} followed by h2.
  size_t szR = al((size_t)N * 4) + al((size_t)N * 8 * 4) + al((size_t)N * 8 * 4);
  if (szR < (size_t)N * 16 * 4) szR = (size_t)N * 16 * 4;
  szR = al(szR);
  size_t szH2 = al((size_t)N * 16 * 4);
  size_t szBig = szR + szH2;
  if (szBig < (size_t)E * 8) szBig = (size_t)E * 8;
  char* bigbuf = alloc(szBig);
  u64*   pairs = (u64*)bigbuf;
  float* agg1  = (float*)bigbuf;
  float* h1    = (float*)(bigbuf + al((size_t)N * 4));
  float* agg2  = (float*)(bigbuf + al((size_t)N * 4) + al((size_t)N * 8 * 4));
  float* agg3  = (float*)bigbuf;
  float* h2    = (float*)(bigbuf + szR);

  unsigned* pooled = (unsigned*)alloc((size_t)B * 32 * 4);
  float*    stats  = (float*)alloc(1024 * 4);

  float* sums0 = stats + 0;
  float* ab0   = stats + 4;
  float* sums1 = stats + 8;
  float* ab1   = stats + 24;
  float* sums2 = stats + 40;
  float* ab2   = stats + 72;
  float* sums3 = stats + 104;
  float* ab3   = stats + 168;

  hipMemsetAsync(stats, 0, 1024 * 4, stream);
  hipMemsetAsync(pooled, 0, (size_t)B * 32 * 4, stream);

  const int T = 256;
  const int gN = (N + T - 1) / T;
  const int gS = 1024;
  const int gX = 512;
  const int nbScanM = (M + 2047) / 2048;

  // bn0 (independent of edges)
  k_s0<<<gS, T, 0, stream>>>(x, N, sums0);
  k_c0<<<1, 1, 0, stream>>>(sums0, bn0_g, bn0_b, invN, ab0);

  // ==== CSR build ====
  k_hist<<<nblk, T, 0, stream>>>(dst, E, nblk, nbk, histG);
  k_scan1<<<nbScanM, T, 0, stream>>>(histG, M, histG, bsum);   // in-place
  k_scan2<<<1, T, 0, stream>>>(bsum, nbScanM);
  k_scan3<<<(M + T - 1) / T, T, 0, stream>>>(histG, bsum, M);  // fixup in-place
  k_binpairs<<<nblk, T, 0, stream>>>(src, dst, E, nblk, nbk, histG, pairs);
  k_bucket_csr<<<nbk, T, 0, stream>>>(pairs, histG, nblk, nbk, E, N, offv, dinv, csr);
  // pairs dead from here; bigbuf reused for layer buffers

  // layer 1 (FI=1 -> FO=8)
  k_gather1<<<gN, T, 0, stream>>>(offv, csr, x, dinv, ab0, N, E, agg1);
  k_stats8<1, 8><<<dim3(gX, 1), T, 0, stream>>>(agg1, W1, b1, N, sums1);
  k_affine<8><<<1, 64, 0, stream>>>(sums1, bn1_g, bn1_b, invN, ab1);
  k_transform<1, 8><<<gN, T, 0, stream>>>(agg1, W1, b1, ab1, N, h1);

  // layer 2 (FI=8 -> FO=16)
  k_gather<8><<<(N * 2 + T - 1) / T, T, 0, stream>>>(offv, csr, h1, dinv, N, E, agg2);
  k_stats8<8, 16><<<dim3(gX, 2), T, 0, stream>>>(agg2, W2, b2, N, sums2);
  k_affine<16><<<1, 64, 0, stream>>>(sums2, bn2_g, bn2_b, invN, ab2);
  k_transform<8, 16><<<gN, T, 0, stream>>>(agg2, W2, b2, ab2, N, h2);

  // layer 3 (FI=16 -> FO=32); agg3 aliases dead agg1/h1/agg2
  k_gather<16><<<(N * 4 + T - 1) / T, T, 0, stream>>>(offv, csr, h2, dinv, N, E, agg3);
  k_stats8<16, 32><<<dim3(gX, 4), T, 0, stream>>>(agg3, W3, b3, N, sums3);
  k_affine<32><<<1, 64, 0, stream>>>(sums3, bn3_g, bn3_b, invN, ab3);
  k_pool<16, 32><<<gN, T, 0, stream>>>(agg3, W3, b3, ab3, batch, N, B, pooled);

  // final MLP
  k_mlp<<<(B + T - 1) / T, T, 0, stream>>>(pooled, L1W, L1b, L2W, L2b, B, (float*)d_out);
}

// Round 7
// 989.350 us; speedup vs baseline: 6.5705x; 1.1228x over previous
//
#include <hip/hip_runtime.h>

#define EPS 1e-5f
#define CHUNK 16384
#define MAXB 512            // max buckets (LDS arrays in hist/binpairs)
#define BSH 10              // nodes per bucket = 1024
#define BNODES (1 << BSH)

typedef unsigned long long u64;

__device__ __forceinline__ float wave_sum(float v) {
  #pragma unroll
  for (int o = 32; o > 0; o >>= 1) v += __shfl_down(v, o, 64);
  return v;
}

__device__ __forceinline__ void atomic_add_f(float* p, float v) {
  unsafeAtomicAdd(p, v);
}

// ---- bn0 stats: sum, sumsq of x ----
__global__ void __launch_bounds__(256) k_s0(const float* __restrict__ x, int N,
                                            float* __restrict__ sums) {
  float s = 0.f, q = 0.f;
  for (int i = blockIdx.x * blockDim.x + threadIdx.x; i < N; i += gridDim.x * blockDim.x) {
    float v = x[i];
    s += v;
    q = fmaf(v, v, q);
  }
  s = wave_sum(s);
  q = wave_sum(q);
  if ((threadIdx.x & 63) == 0) { atomic_add_f(&sums[0], s); atomic_add_f(&sums[1], q); }
}

// ---- bn0 affine ----
__global__ void __launch_bounds__(64) k_c0(const float* __restrict__ sums,
                                           const float* __restrict__ g,
                                           const float* __restrict__ b, float invN,
                                           float* __restrict__ ab) {
  float mu = sums[0] * invN;
  float var = fmaf(-mu, mu, sums[1] * invN);
  float r = rsqrtf(var + EPS);
  float a = g[0] * r;
  ab[0] = a;
  ab[1] = b[0] - mu * a;
}

// ==== Phase A: per-chunk bucket histogram (bucket = dst >> BSH) ====
__global__ void __launch_bounds__(256) k_hist(const int* __restrict__ dst, int E, int nblk,
                                              int nbk, int* __restrict__ histG) {
  __shared__ int h[MAXB];
  for (int t = threadIdx.x; t < nbk; t += blockDim.x) h[t] = 0;
  __syncthreads();
  int base = blockIdx.x * CHUNK;
  int end = base + CHUNK < E ? base + CHUNK : E;
  for (int i = base + threadIdx.x; i < end; i += blockDim.x)
    atomicAdd(&h[dst[i] >> BSH], 1);
  __syncthreads();
  for (int t = threadIdx.x; t < nbk; t += blockDim.x)
    histG[t * nblk + blockIdx.x] = h[t];
}

// ==== Phase C: bin (dst,src) pairs into bucket-contiguous regions (LDS cursors) ====
__global__ void __launch_bounds__(256) k_binpairs(const int* __restrict__ src,
                                                  const int* __restrict__ dst, int E,
                                                  int nblk, int nbk,
                                                  const int* __restrict__ histOff,
                                                  u64* __restrict__ pairs) {
  __shared__ int cur[MAXB];
  for (int t = threadIdx.x; t < nbk; t += blockDim.x)
    cur[t] = histOff[t * nblk + blockIdx.x];
  __syncthreads();
  int base = blockIdx.x * CHUNK;
  int end = base + CHUNK < E ? base + CHUNK : E;
  for (int i = base + threadIdx.x; i < end; i += blockDim.x) {
    int d = dst[i];
    int s = src[i];
    int pos = atomicAdd(&cur[d >> BSH], 1);
    pairs[pos] = ((u64)(unsigned)d << 32) | (unsigned)s;
  }
}

// ==== fused per-bucket: degree -> dinv/offv (global prefix = bucket base) -> csr ====
__global__ void __launch_bounds__(256) k_bucket_csr(const u64* __restrict__ pairs,
                                                    const int* __restrict__ histG,
                                                    int nblk, int nbk, int E, int N,
                                                    int* __restrict__ offv,
                                                    float* __restrict__ dinv,
                                                    int* __restrict__ csr) {
  __shared__ int cnt[BNODES];
  __shared__ int sscan[256];
  int b = blockIdx.x;
  int d0 = b << BSH;
  #pragma unroll
  for (int k = 0; k < BNODES / 256; k++) cnt[threadIdx.x + 256 * k] = 0;
  int beg = histG[(size_t)b * nblk];
  int end = (b + 1 < nbk) ? histG[(size_t)(b + 1) * nblk] : E;
  __syncthreads();

  for (int i = beg + threadIdx.x; i < end; i += 256)
    atomicAdd(&cnt[(int)(pairs[i] >> 32) - d0], 1);
  __syncthreads();

  int base4 = threadIdx.x * 4;
  int v0 = cnt[base4], v1 = cnt[base4 + 1], v2 = cnt[base4 + 2], v3 = cnt[base4 + 3];
  int s = v0 + v1 + v2 + v3;
  sscan[threadIdx.x] = s;
  __syncthreads();
  for (int o = 1; o < 256; o <<= 1) {
    int t2 = (threadIdx.x >= o) ? sscan[threadIdx.x - o] : 0;
    __syncthreads();
    sscan[threadIdx.x] += t2;
    __syncthreads();
  }
  int run = sscan[threadIdx.x] - s;

  {
    int i = d0 + base4;
    if (i < N)     { offv[i] = beg + run;     dinv[i] = rsqrtf((float)v0 + 1.f); }
    cnt[base4] = run; run += v0;
    if (i + 1 < N) { offv[i + 1] = beg + run; dinv[i + 1] = rsqrtf((float)v1 + 1.f); }
    cnt[base4 + 1] = run; run += v1;
    if (i + 2 < N) { offv[i + 2] = beg + run; dinv[i + 2] = rsqrtf((float)v2 + 1.f); }
    cnt[base4 + 2] = run; run += v2;
    if (i + 3 < N) { offv[i + 3] = beg + run; dinv[i + 3] = rsqrtf((float)v3 + 1.f); }
    cnt[base4 + 3] = run; run += v3;
  }
  __syncthreads();

  for (int i = beg + threadIdx.x; i < end; i += 256) {
    u64 p = pairs[i];
    int d = (int)(p >> 32);
    int pos = beg + atomicAdd(&cnt[d - d0], 1);
    csr[pos] = (int)(unsigned)p;
  }
}

// ==== exclusive scan kernels (used for histG only) ====
__global__ void __launch_bounds__(256) k_scan1(const int* __restrict__ cnt, int N,
                                               int* __restrict__ off, int* __restrict__ bsum) {
  __shared__ int lds[256];
  int base = blockIdx.x * 2048 + threadIdx.x * 8;
  int v[8];
  int s = 0;
  #pragma unroll
  for (int k = 0; k < 8; k++) {
    int i = base + k;
    v[k] = (i < N) ? cnt[i] : 0;
    s += v[k];
  }
  lds[threadIdx.x] = s;
  __syncthreads();
  for (int o = 1; o < 256; o <<= 1) {
    int t2 = (threadIdx.x >= o) ? lds[threadIdx.x - o] : 0;
    __syncthreads();
    lds[threadIdx.x] += t2;
    __syncthreads();
  }
  int run = lds[threadIdx.x] - s;
  #pragma unroll
  for (int k = 0; k < 8; k++) {
    int i = base + k;
    if (i < N) off[i] = run;
    run += v[k];
  }
  if (threadIdx.x == 255) bsum[blockIdx.x] = lds[255];
}

__global__ void __launch_bounds__(256) k_scan2(int* __restrict__ bsum, int nb) {
  __shared__ int lds[256];
  int base = threadIdx.x * 8;
  int v[8];
  int s = 0;
  #pragma unroll
  for (int k = 0; k < 8; k++) {
    int i = base + k;
    v[k] = (i < nb) ? bsum[i] : 0;
    s += v[k];
  }
  lds[threadIdx.x] = s;
  __syncthreads();
  for (int o = 1; o < 256; o <<= 1) {
    int t2 = (threadIdx.x >= o) ? lds[threadIdx.x - o] : 0;
    __syncthreads();
    lds[threadIdx.x] += t2;
    __syncthreads();
  }
  int run = lds[threadIdx.x] - s;
  #pragma unroll
  for (int k = 0; k < 8; k++) {
    int i = base + k;
    if (i < nb) bsum[i] = run;
    run += v[k];
  }
}

__global__ void __launch_bounds__(256) k_scan3(int* __restrict__ off,
                                               const int* __restrict__ bsum, int N) {
  int i = blockIdx.x * blockDim.x + threadIdx.x;
  if (i >= N) return;
  off[i] = off[i] + bsum[i >> 11];
}

// ---- layer-1 gather (F=1), 8-wide batched; h0 = x*a+b on the fly ----
__global__ void __launch_bounds__(256) k_gather1(const int* __restrict__ off,
                                                 const int* __restrict__ csr,
                                                 const float* __restrict__ x,
                                                 const float* __restrict__ dinv,
                                                 const float* __restrict__ ab0, int N, int E,
                                                 float* __restrict__ agg) {
  int d = blockIdx.x * blockDim.x + threadIdx.x;
  if (d >= N) return;
  float a = ab0[0], bb = ab0[1];
  int beg = off[d];
  int end = (d + 1 < N) ? off[d + 1] : E;
  float dv = dinv[d];
  float acc = fmaf(x[d], a, bb) * dv * dv;
  int last = end - 1;
  for (int e = beg; e < end; e += 8) {
    int e1 = e + 1 <= last ? e + 1 : last, e2 = e + 2 <= last ? e + 2 : last;
    int e3 = e + 3 <= last ? e + 3 : last, e4 = e + 4 <= last ? e + 4 : last;
    int e5 = e + 5 <= last ? e + 5 : last, e6 = e + 6 <= last ? e + 6 : last;
    int e7 = e + 7 <= last ? e + 7 : last;
    int s0 = csr[e],  s1 = csr[e1], s2 = csr[e2], s3 = csr[e3];
    int s4 = csr[e4], s5 = csr[e5], s6 = csr[e6], s7 = csr[e7];
    float c0 = dinv[s0] * dv;
    float c1 = (e + 1 < end) ? dinv[s1] * dv : 0.f;
    float c2 = (e + 2 < end) ? dinv[s2] * dv : 0.f;
    float c3 = (e + 3 < end) ? dinv[s3] * dv : 0.f;
    float c4 = (e + 4 < end) ? dinv[s4] * dv : 0.f;
    float c5 = (e + 5 < end) ? dinv[s5] * dv : 0.f;
    float c6 = (e + 6 < end) ? dinv[s6] * dv : 0.f;
    float c7 = (e + 7 < end) ? dinv[s7] * dv : 0.f;
    float x0 = x[s0], x1 = x[s1], x2 = x[s2], x3 = x[s3];
    float x4 = x[s4], x5 = x[s5], x6 = x[s6], x7 = x[s7];
    acc = fmaf(c0, fmaf(x0, a, bb), acc);
    acc = fmaf(c1, fmaf(x1, a, bb), acc);
    acc = fmaf(c2, fmaf(x2, a, bb), acc);
    acc = fmaf(c3, fmaf(x3, a, bb), acc);
    acc = fmaf(c4, fmaf(x4, a, bb), acc);
    acc = fmaf(c5, fmaf(x5, a, bb), acc);
    acc = fmaf(c6, fmaf(x6, a, bb), acc);
    acc = fmaf(c7, fmaf(x7, a, bb), acc);
  }
  agg[d] = acc;
}

// ---- generic gather: thread = (node, float4 quad), 4-wide batched edges ----
template<int F>
__global__ void __launch_bounds__(256) k_gather(const int* __restrict__ off,
                                                const int* __restrict__ csr,
                                                const float* __restrict__ h,
                                                const float* __restrict__ dinv, int N, int E,
                                                float* __restrict__ agg) {
  constexpr int Q = F / 4;
  constexpr int SH = (Q == 2) ? 1 : 2;
  int t = blockIdx.x * blockDim.x + threadIdx.x;
  int d = t >> SH;
  if (d >= N) return;
  int q = t & (Q - 1);
  int beg = off[d];
  int end = (d + 1 < N) ? off[d + 1] : E;
  float dv = dinv[d];
  const float4* hp = (const float4*)h;
  float4 acc = hp[(size_t)d * Q + q];
  float c0i = dv * dv;
  acc.x *= c0i; acc.y *= c0i; acc.z *= c0i; acc.w *= c0i;
  int last = end - 1;
  for (int e = beg; e < end; e += 4) {
    int e1 = e + 1 <= last ? e + 1 : last;
    int e2 = e + 2 <= last ? e + 2 : last;
    int e3 = e + 3 <= last ? e + 3 : last;
    int s0 = csr[e], s1 = csr[e1], s2 = csr[e2], s3 = csr[e3];
    float c0 = dinv[s0] * dv;
    float c1 = (e + 1 < end) ? dinv[s1] * dv : 0.f;
    float c2 = (e + 2 < end) ? dinv[s2] * dv : 0.f;
    float c3 = (e + 3 < end) ? dinv[s3] * dv : 0.f;
    float4 v0 = hp[(size_t)s0 * Q + q];
    float4 v1 = hp[(size_t)s1 * Q + q];
    float4 v2 = hp[(size_t)s2 * Q + q];
    float4 v3 = hp[(size_t)s3 * Q + q];
    acc.x = fmaf(c0, v0.x, acc.x); acc.y = fmaf(c0, v0.y, acc.y);
    acc.z = fmaf(c0, v0.z, acc.z); acc.w = fmaf(c0, v0.w, acc.w);
    acc.x = fmaf(c1, v1.x, acc.x); acc.y = fmaf(c1, v1.y, acc.y);
    acc.z = fmaf(c1, v1.z, acc.z); acc.w = fmaf(c1, v1.w, acc.w);
    acc.x = fmaf(c2, v2.x, acc.x); acc.y = fmaf(c2, v2.y, acc.y);
    acc.z = fmaf(c2, v2.z, acc.z); acc.w = fmaf(c2, v2.w, acc.w);
    acc.x = fmaf(c3, v3.x, acc.x); acc.y = fmaf(c3, v3.y, acc.y);
    acc.z = fmaf(c3, v3.z, acc.z); acc.w = fmaf(c3, v3.w, acc.w);
  }
  ((float4*)agg)[(size_t)d * Q + q] = acc;
}

// ==== per-channel stats of y = gW + b, channel-group split (8 channels/block) ====
#define STATS_STEP(GK, K)                                   \
  {                                                         \
    const float gk_ = (GK);                                 \
    const float* wr_ = Wsh + (K) * 8;                       \
    y0.x = fmaf(gk_, wr_[0], y0.x);                         \
    y0.y = fmaf(gk_, wr_[1], y0.y);                         \
    y0.z = fmaf(gk_, wr_[2], y0.z);                         \
    y0.w = fmaf(gk_, wr_[3], y0.w);                         \
    y1.x = fmaf(gk_, wr_[4], y1.x);                         \
    y1.y = fmaf(gk_, wr_[5], y1.y);                         \
    y1.z = fmaf(gk_, wr_[6], y1.z);                         \
    y1.w = fmaf(gk_, wr_[7], y1.w);                         \
  }

template<int FI, int FO>
__global__ void __launch_bounds__(256) k_stats8(const float* __restrict__ g,
                                                const float* __restrict__ W,
                                                const float* __restrict__ b, int N,
                                                float* __restrict__ sums) {
  const int j0 = blockIdx.y * 8;
  __shared__ float Wsh[FI * 8];
  __shared__ float bsh[8];
  __shared__ float red[4][16];
  for (int t = threadIdx.x; t < FI * 8; t += blockDim.x) {
    int k = t >> 3, jj = t & 7;
    Wsh[t] = W[k * FO + j0 + jj];
  }
  if (threadIdx.x < 8) bsh[threadIdx.x] = b[j0 + threadIdx.x];
  __syncthreads();

  float4 s0 = {0.f, 0.f, 0.f, 0.f}, s1 = {0.f, 0.f, 0.f, 0.f};
  float4 q0 = {0.f, 0.f, 0.f, 0.f}, q1 = {0.f, 0.f, 0.f, 0.f};

  for (int i = blockIdx.x * blockDim.x + threadIdx.x; i < N; i += gridDim.x * blockDim.x) {
    float4 y0 = {bsh[0], bsh[1], bsh[2], bsh[3]};
    float4 y1 = {bsh[4], bsh[5], bsh[6], bsh[7]};
    const float* gp = g + (size_t)i * FI;
    if constexpr (FI == 1) {
      STATS_STEP(gp[0], 0)
    } else if constexpr (FI == 8) {
      float4 ga = *(const float4*)gp;
      float4 gb = *(const float4*)(gp + 4);
      STATS_STEP(ga.x, 0) STATS_STEP(ga.y, 1) STATS_STEP(ga.z, 2) STATS_STEP(ga.w, 3)
      STATS_STEP(gb.x, 4) STATS_STEP(gb.y, 5) STATS_STEP(gb.z, 6) STATS_STEP(gb.w, 7)
    } else {
      float4 ga = *(const float4*)gp;
      float4 gb = *(const float4*)(gp + 4);
      float4 gc = *(const float4*)(gp + 8);
      float4 gd = *(const float4*)(gp + 12);
      STATS_STEP(ga.x, 0)  STATS_STEP(ga.y, 1)  STATS_STEP(ga.z, 2)  STATS_STEP(ga.w, 3)
      STATS_STEP(gb.x, 4)  STATS_STEP(gb.y, 5)  STATS_STEP(gb.z, 6)  STATS_STEP(gb.w, 7)
      STATS_STEP(gc.x, 8)  STATS_STEP(gc.y, 9)  STATS_STEP(gc.z, 10) STATS_STEP(gc.w, 11)
      STATS_STEP(gd.x, 12) STATS_STEP(gd.y, 13) STATS_STEP(gd.z, 14) STATS_STEP(gd.w, 15)
    }
    s0.x += y0.x; s0.y += y0.y; s0.z += y0.z; s0.w += y0.w;
    s1.x += y1.x; s1.y += y1.y; s1.z += y1.z; s1.w += y1.w;
    q0.x = fmaf(y0.x, y0.x, q0.x); q0.y = fmaf(y0.y, y0.y, q0.y);
    q0.z = fmaf(y0.z, y0.z, q0.z); q0.w = fmaf(y0.w, y0.w, q0.w);
    q1.x = fmaf(y1.x, y1.x, q1.x); q1.y = fmaf(y1.y, y1.y, q1.y);
    q1.z = fmaf(y1.z, y1.z, q1.z); q1.w = fmaf(y1.w, y1.w, q1.w);
  }

  float vals[16] = {s0.x, s0.y, s0.z, s0.w, s1.x, s1.y, s1.z, s1.w,
                    q0.x, q0.y, q0.z, q0.w, q1.x, q1.y, q1.z, q1.w};
  #pragma unroll
  for (int c = 0; c < 16; c++) vals[c] = wave_sum(vals[c]);

  int wid = threadIdx.x >> 6, lane = threadIdx.x & 63;
  if (lane == 0) {
    #pragma unroll
    for (int c = 0; c < 16; c++) red[wid][c] = vals[c];
  }
  __syncthreads();
  if (threadIdx.x < 16) {
    int c = threadIdx.x;
    float t = red[0][c] + red[1][c] + red[2][c] + red[3][c];
    int j = j0 + (c & 7);
    atomic_add_f((c < 8) ? &sums[j] : &sums[FO + j], t);
  }
}

// ---- fold BN into per-channel affine ----
template<int FO>
__global__ void __launch_bounds__(64) k_affine(const float* __restrict__ sums,
                                               const float* __restrict__ gamma,
                                               const float* __restrict__ beta, float invN,
                                               float* __restrict__ ab) {
  int j = threadIdx.x;
  if (j >= FO) return;
  float mu = sums[j] * invN;
  float var = fmaf(-mu, mu, sums[FO + j] * invN);
  float r = rsqrtf(var + EPS);
  float a = gamma[j] * r;
  ab[j] = a;
  ab[FO + j] = beta[j] - mu * a;
}

// ---- transform: h = relu((gW+b)*alpha+delta) ----
template<int FI, int FO>
__global__ void __launch_bounds__(256) k_transform(const float* __restrict__ g,
                                                   const float* __restrict__ W,
                                                   const float* __restrict__ b,
                                                   const float* __restrict__ ab, int N,
                                                   float* __restrict__ h) {
  __shared__ float Ws[FI * FO];
  __shared__ float bs[FO];
  __shared__ float as2[2 * FO];
  for (int t = threadIdx.x; t < FI * FO; t += blockDim.x) Ws[t] = W[t];
  for (int t = threadIdx.x; t < FO; t += blockDim.x) bs[t] = b[t];
  for (int t = threadIdx.x; t < 2 * FO; t += blockDim.x) as2[t] = ab[t];
  __syncthreads();

  int i = blockIdx.x * blockDim.x + threadIdx.x;
  if (i >= N) return;

  float gv[FI];
  if constexpr (FI % 4 == 0) {
    const float4* g4 = (const float4*)(g + (size_t)i * FI);
    #pragma unroll
    for (int k = 0; k < FI / 4; k++) {
      float4 v = g4[k];
      gv[4 * k] = v.x; gv[4 * k + 1] = v.y; gv[4 * k + 2] = v.z; gv[4 * k + 3] = v.w;
    }
  } else {
    #pragma unroll
    for (int k = 0; k < FI; k++) gv[k] = g[(size_t)i * FI + k];
  }

  #pragma unroll
  for (int jq = 0; jq < FO / 4; jq++) {
    float4 y = {bs[4 * jq], bs[4 * jq + 1], bs[4 * jq + 2], bs[4 * jq + 3]};
    #pragma unroll
    for (int k = 0; k < FI; k++) {
      float gk = gv[k];
      const float* wr = Ws + k * FO + 4 * jq;
      y.x = fmaf(gk, wr[0], y.x);
      y.y = fmaf(gk, wr[1], y.y);
      y.z = fmaf(gk, wr[2], y.z);
      y.w = fmaf(gk, wr[3], y.w);
    }
    float4 o;
    o.x = fmaxf(fmaf(y.x, as2[4 * jq + 0], as2[FO + 4 * jq + 0]), 0.f);
    o.y = fmaxf(fmaf(y.y, as2[4 * jq + 1], as2[FO + 4 * jq + 1]), 0.f);
    o.z = fmaxf(fmaf(y.z, as2[4 * jq + 2], as2[FO + 4 * jq + 2]), 0.f);
    o.w = fmaxf(fmaf(y.w, as2[4 * jq + 3], as2[FO + 4 * jq + 3]), 0.f);
    ((float4*)(h + (size_t)i * FO))[jq] = o;
  }
}

// ---- layer-3 transform fused with segment-max pooling ----
template<int FI, int FO>
__global__ void __launch_bounds__(256) k_pool(const float* __restrict__ g,
                                              const float* __restrict__ W,
                                              const float* __restrict__ b,
                                              const float* __restrict__ ab,
                                              const int* __restrict__ batch, int N, int B,
                                              unsigned* __restrict__ pooled) {
  __shared__ float Ws[FI * FO];
  __shared__ float bs[FO];
  __shared__ float as2[2 * FO];
  __shared__ unsigned lpool[4 * FO];
  __shared__ int gid0s;
  for (int t = threadIdx.x; t < FI * FO; t += blockDim.x) Ws[t] = W[t];
  for (int t = threadIdx.x; t < FO; t += blockDim.x) bs[t] = b[t];
  for (int t = threadIdx.x; t < 2 * FO; t += blockDim.x) as2[t] = ab[t];
  if (threadIdx.x < 4 * FO) lpool[threadIdx.x] = 0u;
  int i0 = blockIdx.x * blockDim.x;
  if (threadIdx.x == 0) gid0s = batch[i0 < N ? i0 : (N - 1)];
  __syncthreads();
  int gid0 = gid0s;

  int i = i0 + threadIdx.x;
  if (i < N) {
    float gv[FI];
    const float4* g4 = (const float4*)(g + (size_t)i * FI);
    #pragma unroll
    for (int k = 0; k < FI / 4; k++) {
      float4 v = g4[k];
      gv[4 * k] = v.x; gv[4 * k + 1] = v.y; gv[4 * k + 2] = v.z; gv[4 * k + 3] = v.w;
    }
    int gid = batch[i];
    int slot = gid - gid0;
    #pragma unroll
    for (int j = 0; j < FO; j++) {
      float y = bs[j];
      #pragma unroll
      for (int k = 0; k < FI; k++) y = fmaf(gv[k], Ws[k * FO + j], y);
      float hv = fmaxf(fmaf(y, as2[j], as2[FO + j]), 0.f);
      unsigned u = __float_as_uint(hv);
      if (slot >= 0 && slot < 4) atomicMax(&lpool[slot * FO + j], u);
      else atomicMax(&pooled[(size_t)gid * FO + j], u);
    }
  }
  __syncthreads();
  for (int t = threadIdx.x; t < 4 * FO; t += blockDim.x) {
    unsigned v = lpool[t];
    int gid = gid0 + t / FO;
    if (v && gid < B) atomicMax(&pooled[(size_t)gid * FO + (t % FO)], v);
  }
}

// ---- final MLP ----
__global__ void __launch_bounds__(256) k_mlp(const unsigned* __restrict__ pooled,
                                             const float* __restrict__ W1,
                                             const float* __restrict__ b1,
                                             const float* __restrict__ W2,
                                             const float* __restrict__ b2, int B,
                                             float* __restrict__ out) {
  int gidx = blockIdx.x * blockDim.x + threadIdx.x;
  if (gidx >= B) return;
  float p[32];
  #pragma unroll
  for (int k = 0; k < 32; k++) p[k] = __uint_as_float(pooled[gidx * 32 + k]);
  float o0 = b2[0], o1 = b2[1];
  for (int j = 0; j < 64; j++) {
    float y = b1[j];
    #pragma unroll
    for (int k = 0; k < 32; k++) y = fmaf(p[k], W1[k * 64 + j], y);
    y = fmaxf(y, 0.f);
    o0 = fmaf(y, W2[j * 2 + 0], o0);
    o1 = fmaf(y, W2[j * 2 + 1], o1);
  }
  out[gidx * 2 + 0] = fmaxf(o0, 0.f);
  out[gidx * 2 + 1] = fmaxf(o1, 0.f);
}

extern "C" void kernel_launch(void* const* d_in, const int* in_sizes, int n_in,
                              void* d_out, int out_size, void* d_ws, size_t ws_size,
                              hipStream_t stream) {
  const float* x     = (const float*)d_in[0];
  const int*   ei    = (const int*)d_in[1];
  const int*   batch = (const int*)d_in[2];
  const float* bn0_g = (const float*)d_in[3];
  const float* bn0_b = (const float*)d_in[4];
  const float* W1    = (const float*)d_in[5];
  const float* b1    = (const float*)d_in[6];
  const float* bn1_g = (const float*)d_in[7];
  const float* bn1_b = (const float*)d_in[8];
  const float* W2    = (const float*)d_in[9];
  const float* b2    = (const float*)d_in[10];
  const float* bn2_g = (const float*)d_in[11];
  const float* bn2_b = (const float*)d_in[12];
  const float* W3    = (const float*)d_in[13];
  const float* b3    = (const float*)d_in[14];
  const float* bn3_g = (const float*)d_in[15];
  const float* bn3_b = (const float*)d_in[16];
  const float* L1W   = (const float*)d_in[17];
  const float* L1b   = (const float*)d_in[18];
  const float* L2W   = (const float*)d_in[19];
  const float* L2b   = (const float*)d_in[20];

  const int N = in_sizes[0];
  const int E = in_sizes[1] / 2;
  const int B = out_size / 2;
  const int* src = ei;
  const int* dst = ei + E;
  const float invN = 1.0f / (float)N;

  const int nbk = (N + BNODES - 1) >> BSH;
  const int nblk = (E + CHUNK - 1) / CHUNK;
  const int M = nbk * nblk;

  char* ws = (char*)d_ws;
  size_t off_b = 0;
  auto alloc = [&](size_t bytes) {
    char* p = ws + off_b;
    off_b += (bytes + 255) & ~(size_t)255;
    return p;
  };
  auto al = [](size_t b) { return (b + 255) & ~(size_t)255; };

  int*      offv   = (int*)alloc((size_t)N * 4);
  float*    dinv   = (float*)alloc((size_t)N * 4);
  int*      bsum   = (int*)alloc(4096 * 4);
  int*      histG  = (int*)alloc((size_t)M * 4);
  int*      csr    = (int*)alloc((size_t)E * 4);

  size_t szR = al((size_t)N * 4) + al((size_t)N * 8 * 4) + al((size_t)N * 8 * 4);
  if (szR < (size_t)N * 16 * 4) szR = (size_t)N * 16 * 4;
  szR = al(szR);
  size_t szH2 = al((size_t)N * 16 * 4);
  size_t szBig = szR + szH2;
  if (szBig < (size_t)E * 8) szBig = (size_t)E * 8;
  char* bigbuf = alloc(szBig);
  u64*   pairs = (u64*)bigbuf;
  float* agg1  = (float*)bigbuf;
  float* h1    = (float*)(bigbuf + al((size_t)N * 4));
  float* agg2  = (float*)(bigbuf + al((size_t)N * 4) + al((size_t)N * 8 * 4));
  float* agg3  = (float*)bigbuf;
  float* h2    = (float*)(bigbuf + szR);

  unsigned* pooled = (unsigned*)alloc((size_t)B * 32 * 4);
  float*    stats  = (float*)alloc(1024 * 4);

  float* sums0 = stats + 0;
  float* ab0   = stats + 4;
  float* sums1 = stats + 8;
  float* ab1   = stats + 24;
  float* sums2 = stats + 40;
  float* ab2   = stats + 72;
  float* sums3 = stats + 104;
  float* ab3   = stats + 168;

  hipMemsetAsync(stats, 0, 1024 * 4, stream);
  hipMemsetAsync(pooled, 0, (size_t)B * 32 * 4, stream);

  const int T = 256;
  const int gN = (N + T - 1) / T;
  const int gS = 1024;
  const int gX = 512;
  const int nbScanM = (M + 2047) / 2048;

  k_s0<<<gS, T, 0, stream>>>(x, N, sums0);
  k_c0<<<1, 1, 0, stream>>>(sums0, bn0_g, bn0_b, invN, ab0);

  // ==== CSR build ====
  k_hist<<<nblk, T, 0, stream>>>(dst, E, nblk, nbk, histG);
  k_scan1<<<nbScanM, T, 0, stream>>>(histG, M, histG, bsum);
  k_scan2<<<1, T, 0, stream>>>(bsum, nbScanM);
  k_scan3<<<(M + T - 1) / T, T, 0, stream>>>(histG, bsum, M);
  k_binpairs<<<nblk, T, 0, stream>>>(src, dst, E, nblk, nbk, histG, pairs);
  k_bucket_csr<<<nbk, T, 0, stream>>>(pairs, histG, nblk, nbk, E, N, offv, dinv, csr);

  // layer 1 (FI=1 -> FO=8)
  k_gather1<<<gN, T, 0, stream>>>(offv, csr, x, dinv, ab0, N, E, agg1);
  k_stats8<1, 8><<<dim3(gX, 1), T, 0, stream>>>(agg1, W1, b1, N, sums1);
  k_affine<8><<<1, 64, 0, stream>>>(sums1, bn1_g, bn1_b, invN, ab1);
  k_transform<1, 8><<<gN, T, 0, stream>>>(agg1, W1, b1, ab1, N, h1);

  // layer 2 (FI=8 -> FO=16)
  k_gather<8><<<(N * 2 + T - 1) / T, T, 0, stream>>>(offv, csr, h1, dinv, N, E, agg2);
  k_stats8<8, 16><<<dim3(gX, 2), T, 0, stream>>>(agg2, W2, b2, N, sums2);
  k_affine<16><<<1, 64, 0, stream>>>(sums2, bn2_g, bn2_b, invN, ab2);
  k_transform<8, 16><<<gN, T, 0, stream>>>(agg2, W2, b2, ab2, N, h2);

  // layer 3 (FI=16 -> FO=32)
  k_gather<16><<<(N * 4 + T - 1) / T, T, 0, stream>>>(offv, csr, h2, dinv, N, E, agg3);
  k_stats8<16, 32><<<dim3(gX, 4), T, 0, stream>>>(agg3, W3, b3, N, sums3);
  k_affine<32><<<1, 64, 0, stream>>>(sums3, bn3_g, bn3_b, invN, ab3);
  k_pool<16, 32><<<gN, T, 0, stream>>>(agg3, W3, b3, ab3, batch, N, B, pooled);

  // final MLP
  k_mlp<<<(B + T - 1) / T, T, 0, stream>>>(pooled, L1W, L1b, L2W, L2b, B, (float*)d_out);
}

// Round 8
// 804.827 us; speedup vs baseline: 8.0769x; 1.2293x over previous
//
#include <hip/hip_runtime.h>

#define EPS 1e-5f
#define CHUNK 16384
#define MAXB 512            // max buckets (LDS arrays in hist/binpairs)
#define BSH 10              // nodes per bucket = 1024
#define BNODES (1 << BSH)
#define SRCMASK 0x3FFFFF    // 22 bits for src id (N <= 4M)

typedef unsigned int u32;

__device__ __forceinline__ float wave_sum(float v) {
  #pragma unroll
  for (int o = 32; o > 0; o >>= 1) v += __shfl_down(v, o, 64);
  return v;
}

__device__ __forceinline__ void atomic_add_f(float* p, float v) {
  unsafeAtomicAdd(p, v);
}

// ---- bn0 stats: sum, sumsq of x ----
__global__ void __launch_bounds__(256) k_s0(const float* __restrict__ x, int N,
                                            float* __restrict__ sums) {
  float s = 0.f, q = 0.f;
  for (int i = blockIdx.x * blockDim.x + threadIdx.x; i < N; i += gridDim.x * blockDim.x) {
    float v = x[i];
    s += v;
    q = fmaf(v, v, q);
  }
  s = wave_sum(s);
  q = wave_sum(q);
  if ((threadIdx.x & 63) == 0) { atomic_add_f(&sums[0], s); atomic_add_f(&sums[1], q); }
}

// ---- bn0 affine ----
__global__ void __launch_bounds__(64) k_c0(const float* __restrict__ sums,
                                           const float* __restrict__ g,
                                           const float* __restrict__ b, float invN,
                                           float* __restrict__ ab) {
  float mu = sums[0] * invN;
  float var = fmaf(-mu, mu, sums[1] * invN);
  float r = rsqrtf(var + EPS);
  float a = g[0] * r;
  ab[0] = a;
  ab[1] = b[0] - mu * a;
}

// ==== Phase A: per-chunk bucket histogram (bucket = dst >> BSH) ====
__global__ void __launch_bounds__(256) k_hist(const int* __restrict__ dst, int E, int nblk,
                                              int nbk, int* __restrict__ histG) {
  __shared__ int h[MAXB];
  for (int t = threadIdx.x; t < nbk; t += blockDim.x) h[t] = 0;
  __syncthreads();
  int base = blockIdx.x * CHUNK;
  int end = base + CHUNK < E ? base + CHUNK : E;
  for (int i = base + threadIdx.x; i < end; i += blockDim.x)
    atomicAdd(&h[dst[i] >> BSH], 1);
  __syncthreads();
  for (int t = threadIdx.x; t < nbk; t += blockDim.x)
    histG[t * nblk + blockIdx.x] = h[t];
}

// ==== Phase C: bin packed (dlocal,src) into bucket-contiguous regions ====
__global__ void __launch_bounds__(256) k_binpairs(const int* __restrict__ src,
                                                  const int* __restrict__ dst, int E,
                                                  int nblk, int nbk,
                                                  const int* __restrict__ histOff,
                                                  u32* __restrict__ pairs) {
  __shared__ int cur[MAXB];
  for (int t = threadIdx.x; t < nbk; t += blockDim.x)
    cur[t] = histOff[t * nblk + blockIdx.x];
  __syncthreads();
  int base = blockIdx.x * CHUNK;
  int end = base + CHUNK < E ? base + CHUNK : E;
  for (int i = base + threadIdx.x; i < end; i += blockDim.x) {
    int d = dst[i];
    int s = src[i];
    int pos = atomicAdd(&cur[d >> BSH], 1);
    pairs[pos] = ((u32)(d & (BNODES - 1)) << 22) | (u32)s;
  }
}

// ==== fused per-bucket: degree -> dinv/offv/h0s -> csr (block-exclusive writes) ====
__global__ void __launch_bounds__(256) k_bucket_csr(const u32* __restrict__ pairs,
                                                    const int* __restrict__ histG,
                                                    const float* __restrict__ x,
                                                    const float* __restrict__ ab0,
                                                    int nblk, int nbk, int E, int N,
                                                    int* __restrict__ offv,
                                                    float* __restrict__ dinv,
                                                    float* __restrict__ h0s,
                                                    int* __restrict__ csr) {
  __shared__ int cnt[BNODES];
  __shared__ int sscan[256];
  int b = blockIdx.x;
  int d0 = b << BSH;
  #pragma unroll
  for (int k = 0; k < BNODES / 256; k++) cnt[threadIdx.x + 256 * k] = 0;
  int beg = histG[(size_t)b * nblk];
  int end = (b + 1 < nbk) ? histG[(size_t)(b + 1) * nblk] : E;
  __syncthreads();

  for (int i = beg + threadIdx.x; i < end; i += 256)
    atomicAdd(&cnt[pairs[i] >> 22], 1);
  __syncthreads();

  int base4 = threadIdx.x * 4;
  int v0 = cnt[base4], v1 = cnt[base4 + 1], v2 = cnt[base4 + 2], v3 = cnt[base4 + 3];
  int s = v0 + v1 + v2 + v3;
  sscan[threadIdx.x] = s;
  __syncthreads();
  for (int o = 1; o < 256; o <<= 1) {
    int t2 = (threadIdx.x >= o) ? sscan[threadIdx.x - o] : 0;
    __syncthreads();
    sscan[threadIdx.x] += t2;
    __syncthreads();
  }
  int run = sscan[threadIdx.x] - s;

  {
    float a = ab0[0], bb = ab0[1];
    int i = d0 + base4;
    if (i < N) {
      float dv = rsqrtf((float)v0 + 1.f);
      offv[i] = beg + run; dinv[i] = dv; h0s[i] = fmaf(x[i], a, bb) * dv;
    }
    cnt[base4] = run; run += v0;
    if (i + 1 < N) {
      float dv = rsqrtf((float)v1 + 1.f);
      offv[i + 1] = beg + run; dinv[i + 1] = dv; h0s[i + 1] = fmaf(x[i + 1], a, bb) * dv;
    }
    cnt[base4 + 1] = run; run += v1;
    if (i + 2 < N) {
      float dv = rsqrtf((float)v2 + 1.f);
      offv[i + 2] = beg + run; dinv[i + 2] = dv; h0s[i + 2] = fmaf(x[i + 2], a, bb) * dv;
    }
    cnt[base4 + 2] = run; run += v2;
    if (i + 3 < N) {
      float dv = rsqrtf((float)v3 + 1.f);
      offv[i + 3] = beg + run; dinv[i + 3] = dv; h0s[i + 3] = fmaf(x[i + 3], a, bb) * dv;
    }
    cnt[base4 + 3] = run; run += v3;
  }
  __syncthreads();

  for (int i = beg + threadIdx.x; i < end; i += 256) {
    u32 p = pairs[i];
    int dl = p >> 22;
    int pos = beg + atomicAdd(&cnt[dl], 1);
    csr[pos] = (int)(p & SRCMASK);
  }
}

// ==== exclusive scan kernels (used for histG only) ====
__global__ void __launch_bounds__(256) k_scan1(const int* __restrict__ cnt, int N,
                                               int* __restrict__ off, int* __restrict__ bsum) {
  __shared__ int lds[256];
  int base = blockIdx.x * 2048 + threadIdx.x * 8;
  int v[8];
  int s = 0;
  #pragma unroll
  for (int k = 0; k < 8; k++) {
    int i = base + k;
    v[k] = (i < N) ? cnt[i] : 0;
    s += v[k];
  }
  lds[threadIdx.x] = s;
  __syncthreads();
  for (int o = 1; o < 256; o <<= 1) {
    int t2 = (threadIdx.x >= o) ? lds[threadIdx.x - o] : 0;
    __syncthreads();
    lds[threadIdx.x] += t2;
    __syncthreads();
  }
  int run = lds[threadIdx.x] - s;
  #pragma unroll
  for (int k = 0; k < 8; k++) {
    int i = base + k;
    if (i < N) off[i] = run;
    run += v[k];
  }
  if (threadIdx.x == 255) bsum[blockIdx.x] = lds[255];
}

__global__ void __launch_bounds__(256) k_scan2(int* __restrict__ bsum, int nb) {
  __shared__ int lds[256];
  int base = threadIdx.x * 8;
  int v[8];
  int s = 0;
  #pragma unroll
  for (int k = 0; k < 8; k++) {
    int i = base + k;
    v[k] = (i < nb) ? bsum[i] : 0;
    s += v[k];
  }
  lds[threadIdx.x] = s;
  __syncthreads();
  for (int o = 1; o < 256; o <<= 1) {
    int t2 = (threadIdx.x >= o) ? lds[threadIdx.x - o] : 0;
    __syncthreads();
    lds[threadIdx.x] += t2;
    __syncthreads();
  }
  int run = lds[threadIdx.x] - s;
  #pragma unroll
  for (int k = 0; k < 8; k++) {
    int i = base + k;
    if (i < nb) bsum[i] = run;
    run += v[k];
  }
}

__global__ void __launch_bounds__(256) k_scan3(int* __restrict__ off,
                                               const int* __restrict__ bsum, int N) {
  int i = blockIdx.x * blockDim.x + threadIdx.x;
  if (i >= N) return;
  off[i] = off[i] + bsum[i >> 11];
}

// ---- layer-1 gather (F=1): agg = dinv[d]*(h0s[d] + sum h0s[s]), 8-wide ----
__global__ void __launch_bounds__(256) k_gather1(const int* __restrict__ off,
                                                 const int* __restrict__ csr,
                                                 const float* __restrict__ h0s,
                                                 const float* __restrict__ dinv, int N, int E,
                                                 float* __restrict__ agg) {
  int d = blockIdx.x * blockDim.x + threadIdx.x;
  if (d >= N) return;
  int beg = off[d];
  int end = (d + 1 < N) ? off[d + 1] : E;
  float acc = h0s[d];
  int last = end - 1;
  for (int e = beg; e < end; e += 8) {
    int e1 = e + 1 <= last ? e + 1 : last, e2 = e + 2 <= last ? e + 2 : last;
    int e3 = e + 3 <= last ? e + 3 : last, e4 = e + 4 <= last ? e + 4 : last;
    int e5 = e + 5 <= last ? e + 5 : last, e6 = e + 6 <= last ? e + 6 : last;
    int e7 = e + 7 <= last ? e + 7 : last;
    int s0 = csr[e],  s1 = csr[e1], s2 = csr[e2], s3 = csr[e3];
    int s4 = csr[e4], s5 = csr[e5], s6 = csr[e6], s7 = csr[e7];
    float m1 = (e + 1 < end) ? 1.f : 0.f, m2 = (e + 2 < end) ? 1.f : 0.f;
    float m3 = (e + 3 < end) ? 1.f : 0.f, m4 = (e + 4 < end) ? 1.f : 0.f;
    float m5 = (e + 5 < end) ? 1.f : 0.f, m6 = (e + 6 < end) ? 1.f : 0.f;
    float m7 = (e + 7 < end) ? 1.f : 0.f;
    acc += h0s[s0];
    acc = fmaf(m1, h0s[s1], acc);
    acc = fmaf(m2, h0s[s2], acc);
    acc = fmaf(m3, h0s[s3], acc);
    acc = fmaf(m4, h0s[s4], acc);
    acc = fmaf(m5, h0s[s5], acc);
    acc = fmaf(m6, h0s[s6], acc);
    acc = fmaf(m7, h0s[s7], acc);
  }
  agg[d] = acc * dinv[d];
}

// ---- generic gather over pre-scaled h: agg = dinv[d]*(h[d] + sum h[s]), 8-wide ----
template<int F>
__global__ void __launch_bounds__(256) k_gather(const int* __restrict__ off,
                                                const int* __restrict__ csr,
                                                const float* __restrict__ h,
                                                const float* __restrict__ dinv, int N, int E,
                                                float* __restrict__ agg) {
  constexpr int Q = F / 4;
  constexpr int SH = (Q == 2) ? 1 : 2;
  int t = blockIdx.x * blockDim.x + threadIdx.x;
  int d = t >> SH;
  if (d >= N) return;
  int q = t & (Q - 1);
  int beg = off[d];
  int end = (d + 1 < N) ? off[d + 1] : E;
  float dv = dinv[d];
  const float4* hp = (const float4*)h;
  float4 acc = hp[(size_t)d * Q + q];
  int last = end - 1;
  for (int e = beg; e < end; e += 8) {
    int e1 = e + 1 <= last ? e + 1 : last, e2 = e + 2 <= last ? e + 2 : last;
    int e3 = e + 3 <= last ? e + 3 : last, e4 = e + 4 <= last ? e + 4 : last;
    int e5 = e + 5 <= last ? e + 5 : last, e6 = e + 6 <= last ? e + 6 : last;
    int e7 = e + 7 <= last ? e + 7 : last;
    int s0 = csr[e],  s1 = csr[e1], s2 = csr[e2], s3 = csr[e3];
    int s4 = csr[e4], s5 = csr[e5], s6 = csr[e6], s7 = csr[e7];
    float4 v0 = hp[(size_t)s0 * Q + q];
    float4 v1 = hp[(size_t)s1 * Q + q];
    float4 v2 = hp[(size_t)s2 * Q + q];
    float4 v3 = hp[(size_t)s3 * Q + q];
    float4 v4 = hp[(size_t)s4 * Q + q];
    float4 v5 = hp[(size_t)s5 * Q + q];
    float4 v6 = hp[(size_t)s6 * Q + q];
    float4 v7 = hp[(size_t)s7 * Q + q];
    float m1 = (e + 1 < end) ? 1.f : 0.f, m2 = (e + 2 < end) ? 1.f : 0.f;
    float m3 = (e + 3 < end) ? 1.f : 0.f, m4 = (e + 4 < end) ? 1.f : 0.f;
    float m5 = (e + 5 < end) ? 1.f : 0.f, m6 = (e + 6 < end) ? 1.f : 0.f;
    float m7 = (e + 7 < end) ? 1.f : 0.f;
    acc.x += v0.x; acc.y += v0.y; acc.z += v0.z; acc.w += v0.w;
    acc.x = fmaf(m1, v1.x, acc.x); acc.y = fmaf(m1, v1.y, acc.y);
    acc.z = fmaf(m1, v1.z, acc.z); acc.w = fmaf(m1, v1.w, acc.w);
    acc.x = fmaf(m2, v2.x, acc.x); acc.y = fmaf(m2, v2.y, acc.y);
    acc.z = fmaf(m2, v2.z, acc.z); acc.w = fmaf(m2, v2.w, acc.w);
    acc.x = fmaf(m3, v3.x, acc.x); acc.y = fmaf(m3, v3.y, acc.y);
    acc.z = fmaf(m3, v3.z, acc.z); acc.w = fmaf(m3, v3.w, acc.w);
    acc.x = fmaf(m4, v4.x, acc.x); acc.y = fmaf(m4, v4.y, acc.y);
    acc.z = fmaf(m4, v4.z, acc.z); acc.w = fmaf(m4, v4.w, acc.w);
    acc.x = fmaf(m5, v5.x, acc.x); acc.y = fmaf(m5, v5.y, acc.y);
    acc.z = fmaf(m5, v5.z, acc.z); acc.w = fmaf(m5, v5.w, acc.w);
    acc.x = fmaf(m6, v6.x, acc.x); acc.y = fmaf(m6, v6.y, acc.y);
    acc.z = fmaf(m6, v6.z, acc.z); acc.w = fmaf(m6, v6.w, acc.w);
    acc.x = fmaf(m7, v7.x, acc.x); acc.y = fmaf(m7, v7.y, acc.y);
    acc.z = fmaf(m7, v7.z, acc.z); acc.w = fmaf(m7, v7.w, acc.w);
  }
  acc.x *= dv; acc.y *= dv; acc.z *= dv; acc.w *= dv;
  ((float4*)agg)[(size_t)d * Q + q] = acc;
}

// ==== stats, 8 channels/block (FO=8) ====
#define STATS_STEP(GK, K)                                   \
  {                                                         \
    const float gk_ = (GK);                                 \
    const float* wr_ = Wsh + (K) * 8;                       \
    y0.x = fmaf(gk_, wr_[0], y0.x);                         \
    y0.y = fmaf(gk_, wr_[1], y0.y);                         \
    y0.z = fmaf(gk_, wr_[2], y0.z);                         \
    y0.w = fmaf(gk_, wr_[3], y0.w);                         \
    y1.x = fmaf(gk_, wr_[4], y1.x);                         \
    y1.y = fmaf(gk_, wr_[5], y1.y);                         \
    y1.z = fmaf(gk_, wr_[6], y1.z);                         \
    y1.w = fmaf(gk_, wr_[7], y1.w);                         \
  }

template<int FI, int FO>
__global__ void __launch_bounds__(256) k_stats8(const float* __restrict__ g,
                                                const float* __restrict__ W,
                                                const float* __restrict__ b, int N,
                                                float* __restrict__ sums) {
  const int j0 = blockIdx.y * 8;
  __shared__ float Wsh[FI * 8];
  __shared__ float bsh[8];
  __shared__ float red[4][16];
  for (int t = threadIdx.x; t < FI * 8; t += blockDim.x) {
    int k = t >> 3, jj = t & 7;
    Wsh[t] = W[k * FO + j0 + jj];
  }
  if (threadIdx.x < 8) bsh[threadIdx.x] = b[j0 + threadIdx.x];
  __syncthreads();

  float4 s0 = {0.f, 0.f, 0.f, 0.f}, s1 = {0.f, 0.f, 0.f, 0.f};
  float4 q0 = {0.f, 0.f, 0.f, 0.f}, q1 = {0.f, 0.f, 0.f, 0.f};

  for (int i = blockIdx.x * blockDim.x + threadIdx.x; i < N; i += gridDim.x * blockDim.x) {
    float4 y0 = {bsh[0], bsh[1], bsh[2], bsh[3]};
    float4 y1 = {bsh[4], bsh[5], bsh[6], bsh[7]};
    const float* gp = g + (size_t)i * FI;
    if constexpr (FI == 1) {
      STATS_STEP(gp[0], 0)
    } else {
      float4 ga = *(const float4*)gp;
      float4 gb = *(const float4*)(gp + 4);
      STATS_STEP(ga.x, 0) STATS_STEP(ga.y, 1) STATS_STEP(ga.z, 2) STATS_STEP(ga.w, 3)
      STATS_STEP(gb.x, 4) STATS_STEP(gb.y, 5) STATS_STEP(gb.z, 6) STATS_STEP(gb.w, 7)
    }
    s0.x += y0.x; s0.y += y0.y; s0.z += y0.z; s0.w += y0.w;
    s1.x += y1.x; s1.y += y1.y; s1.z += y1.z; s1.w += y1.w;
    q0.x = fmaf(y0.x, y0.x, q0.x); q0.y = fmaf(y0.y, y0.y, q0.y);
    q0.z = fmaf(y0.z, y0.z, q0.z); q0.w = fmaf(y0.w, y0.w, q0.w);
    q1.x = fmaf(y1.x, y1.x, q1.x); q1.y = fmaf(y1.y, y1.y, q1.y);
    q1.z = fmaf(y1.z, y1.z, q1.z); q1.w = fmaf(y1.w, y1.w, q1.w);
  }

  float vals[16] = {s0.x, s0.y, s0.z, s0.w, s1.x, s1.y, s1.z, s1.w,
                    q0.x, q0.y, q0.z, q0.w, q1.x, q1.y, q1.z, q1.w};
  #pragma unroll
  for (int c = 0; c < 16; c++) vals[c] = wave_sum(vals[c]);

  int wid = threadIdx.x >> 6, lane = threadIdx.x & 63;
  if (lane == 0) {
    #pragma unroll
    for (int c = 0; c < 16; c++) red[wid][c] = vals[c];
  }
  __syncthreads();
  if (threadIdx.x < 16) {
    int c = threadIdx.x;
    float t = red[0][c] + red[1][c] + red[2][c] + red[3][c];
    int j = j0 + (c & 7);
    atomic_add_f((c < 8) ? &sums[j] : &sums[FO + j], t);
  }
}

// ==== stats, 16 channels/block (FO=16/32) ====
#define STATS_STEP16(GK, K)                                  \
  {                                                          \
    const float gk_ = (GK);                                  \
    const float* wr_ = Wsh + (K) * 16;                       \
    y0.x = fmaf(gk_, wr_[0], y0.x);                          \
    y0.y = fmaf(gk_, wr_[1], y0.y);                          \
    y0.z = fmaf(gk_, wr_[2], y0.z);                          \
    y0.w = fmaf(gk_, wr_[3], y0.w);                          \
    y1.x = fmaf(gk_, wr_[4], y1.x);                          \
    y1.y = fmaf(gk_, wr_[5], y1.y);                          \
    y1.z = fmaf(gk_, wr_[6], y1.z);                          \
    y1.w = fmaf(gk_, wr_[7], y1.w);                          \
    y2.x = fmaf(gk_, wr_[8], y2.x);                          \
    y2.y = fmaf(gk_, wr_[9], y2.y);                          \
    y2.z = fmaf(gk_, wr_[10], y2.z);                         \
    y2.w = fmaf(gk_, wr_[11], y2.w);                         \
    y3.x = fmaf(gk_, wr_[12], y3.x);                         \
    y3.y = fmaf(gk_, wr_[13], y3.y);                         \
    y3.z = fmaf(gk_, wr_[14], y3.z);                         \
    y3.w = fmaf(gk_, wr_[15], y3.w);                         \
  }

template<int FI, int FO>
__global__ void __launch_bounds__(256) k_stats16(const float* __restrict__ g,
                                                 const float* __restrict__ W,
                                                 const float* __restrict__ b, int N,
                                                 float* __restrict__ sums) {
  const int j0 = blockIdx.y * 16;
  __shared__ float Wsh[FI * 16];
  __shared__ float bsh[16];
  __shared__ float red[4][32];
  for (int t = threadIdx.x; t < FI * 16; t += blockDim.x) {
    int k = t >> 4, jj = t & 15;
    Wsh[t] = W[k * FO + j0 + jj];
  }
  if (threadIdx.x < 16) bsh[threadIdx.x] = b[j0 + threadIdx.x];
  __syncthreads();

  float4 s0 = {0.f, 0.f, 0.f, 0.f}, s1 = {0.f, 0.f, 0.f, 0.f};
  float4 s2 = {0.f, 0.f, 0.f, 0.f}, s3 = {0.f, 0.f, 0.f, 0.f};
  float4 q0 = {0.f, 0.f, 0.f, 0.f}, q1 = {0.f, 0.f, 0.f, 0.f};
  float4 q2 = {0.f, 0.f, 0.f, 0.f}, q3 = {0.f, 0.f, 0.f, 0.f};

  for (int i = blockIdx.x * blockDim.x + threadIdx.x; i < N; i += gridDim.x * blockDim.x) {
    float4 y0 = {bsh[0], bsh[1], bsh[2], bsh[3]};
    float4 y1 = {bsh[4], bsh[5], bsh[6], bsh[7]};
    float4 y2 = {bsh[8], bsh[9], bsh[10], bsh[11]};
    float4 y3 = {bsh[12], bsh[13], bsh[14], bsh[15]};
    const float* gp = g + (size_t)i * FI;
    if constexpr (FI == 8) {
      float4 ga = *(const float4*)gp;
      float4 gb = *(const float4*)(gp + 4);
      STATS_STEP16(ga.x, 0) STATS_STEP16(ga.y, 1) STATS_STEP16(ga.z, 2) STATS_STEP16(ga.w, 3)
      STATS_STEP16(gb.x, 4) STATS_STEP16(gb.y, 5) STATS_STEP16(gb.z, 6) STATS_STEP16(gb.w, 7)
    } else {
      float4 ga = *(const float4*)gp;
      float4 gb = *(const float4*)(gp + 4);
      float4 gc = *(const float4*)(gp + 8);
      float4 gd = *(const float4*)(gp + 12);
      STATS_STEP16(ga.x, 0)  STATS_STEP16(ga.y, 1)  STATS_STEP16(ga.z, 2)  STATS_STEP16(ga.w, 3)
      STATS_STEP16(gb.x, 4)  STATS_STEP16(gb.y, 5)  STATS_STEP16(gb.z, 6)  STATS_STEP16(gb.w, 7)
      STATS_STEP16(gc.x, 8)  STATS_STEP16(gc.y, 9)  STATS_STEP16(gc.z, 10) STATS_STEP16(gc.w, 11)
      STATS_STEP16(gd.x, 12) STATS_STEP16(gd.y, 13) STATS_STEP16(gd.z, 14) STATS_STEP16(gd.w, 15)
    }
    s0.x += y0.x; s0.y += y0.y; s0.z += y0.z; s0.w += y0.w;
    s1.x += y1.x; s1.y += y1.y; s1.z += y1.z; s1.w += y1.w;
    s2.x += y2.x; s2.y += y2.y; s2.z += y2.z; s2.w += y2.w;
    s3.x += y3.x; s3.y += y3.y; s3.z += y3.z; s3.w += y3.w;
    q0.x = fmaf(y0.x, y0.x, q0.x); q0.y = fmaf(y0.y, y0.y, q0.y);
    q0.z = fmaf(y0.z, y0.z, q0.z); q0.w = fmaf(y0.w, y0.w, q0.w);
    q1.x = fmaf(y1.x, y1.x, q1.x); q1.y = fmaf(y1.y, y1.y, q1.y);
    q1.z = fmaf(y1.z, y1.z, q1.z); q1.w = fmaf(y1.w, y1.w, q1.w);
    q2.x = fmaf(y2.x, y2.x, q2.x); q2.y = fmaf(y2.y, y2.y, q2.y);
    q2.z = fmaf(y2.z, y2.z, q2.z); q2.w = fmaf(y2.w, y2.w, q2.w);
    q3.x = fmaf(y3.x, y3.x, q3.x); q3.y = fmaf(y3.y, y3.y, q3.y);
    q3.z = fmaf(y3.z, y3.z, q3.z); q3.w = fmaf(y3.w, y3.w, q3.w);
  }

  float vals[32] = {s0.x, s0.y, s0.z, s0.w, s1.x, s1.y, s1.z, s1.w,
                    s2.x, s2.y, s2.z, s2.w, s3.x, s3.y, s3.z, s3.w,
                    q0.x, q0.y, q0.z, q0.w, q1.x, q1.y, q1.z, q1.w,
                    q2.x, q2.y, q2.z, q2.w, q3.x, q3.y, q3.z, q3.w};
  #pragma unroll
  for (int c = 0; c < 32; c++) vals[c] = wave_sum(vals[c]);

  int wid = threadIdx.x >> 6, lane = threadIdx.x & 63;
  if (lane == 0) {
    #pragma unroll
    for (int c = 0; c < 32; c++) red[wid][c] = vals[c];
  }
  __syncthreads();
  if (threadIdx.x < 32) {
    int c = threadIdx.x;
    float t = red[0][c] + red[1][c] + red[2][c] + red[3][c];
    int j = j0 + (c & 15);
    atomic_add_f((c < 16) ? &sums[j] : &sums[FO + j], t);
  }
}

// ---- fold BN into per-channel affine ----
template<int FO>
__global__ void __launch_bounds__(64) k_affine(const float* __restrict__ sums,
                                               const float* __restrict__ gamma,
                                               const float* __restrict__ beta, float invN,
                                               float* __restrict__ ab) {
  int j = threadIdx.x;
  if (j >= FO) return;
  float mu = sums[j] * invN;
  float var = fmaf(-mu, mu, sums[FO + j] * invN);
  float r = rsqrtf(var + EPS);
  float a = gamma[j] * r;
  ab[j] = a;
  ab[FO + j] = beta[j] - mu * a;
}

// ---- transform: h = relu((gW+b)*alpha+delta) * dinv  (pre-scaled for next gather) ----
template<int FI, int FO>
__global__ void __launch_bounds__(256) k_transform(const float* __restrict__ g,
                                                   const float* __restrict__ W,
                                                   const float* __restrict__ b,
                                                   const float* __restrict__ ab,
                                                   const float* __restrict__ dinv, int N,
                                                   float* __restrict__ h) {
  __shared__ float Ws[FI * FO];
  __shared__ float bs[FO];
  __shared__ float as2[2 * FO];
  for (int t = threadIdx.x; t < FI * FO; t += blockDim.x) Ws[t] = W[t];
  for (int t = threadIdx.x; t < FO; t += blockDim.x) bs[t] = b[t];
  for (int t = threadIdx.x; t < 2 * FO; t += blockDim.x) as2[t] = ab[t];
  __syncthreads();

  int i = blockIdx.x * blockDim.x + threadIdx.x;
  if (i >= N) return;

  float gv[FI];
  if constexpr (FI % 4 == 0) {
    const float4* g4 = (const float4*)(g + (size_t)i * FI);
    #pragma unroll
    for (int k = 0; k < FI / 4; k++) {
      float4 v = g4[k];
      gv[4 * k] = v.x; gv[4 * k + 1] = v.y; gv[4 * k + 2] = v.z; gv[4 * k + 3] = v.w;
    }
  } else {
    #pragma unroll
    for (int k = 0; k < FI; k++) gv[k] = g[(size_t)i * FI + k];
  }

  float dvi = dinv[i];
  #pragma unroll
  for (int jq = 0; jq < FO / 4; jq++) {
    float4 y = {bs[4 * jq], bs[4 * jq + 1], bs[4 * jq + 2], bs[4 * jq + 3]};
    #pragma unroll
    for (int k = 0; k < FI; k++) {
      float gk = gv[k];
      const float* wr = Ws + k * FO + 4 * jq;
      y.x = fmaf(gk, wr[0], y.x);
      y.y = fmaf(gk, wr[1], y.y);
      y.z = fmaf(gk, wr[2], y.z);
      y.w = fmaf(gk, wr[3], y.w);
    }
    float4 o;
    o.x = fmaxf(fmaf(y.x, as2[4 * jq + 0], as2[FO + 4 * jq + 0]), 0.f) * dvi;
    o.y = fmaxf(fmaf(y.y, as2[4 * jq + 1], as2[FO + 4 * jq + 1]), 0.f) * dvi;
    o.z = fmaxf(fmaf(y.z, as2[4 * jq + 2], as2[FO + 4 * jq + 2]), 0.f) * dvi;
    o.w = fmaxf(fmaf(y.w, as2[4 * jq + 3], as2[FO + 4 * jq + 3]), 0.f) * dvi;
    ((float4*)(h + (size_t)i * FO))[jq] = o;
  }
}

// ---- layer-3 transform fused with segment-max pooling ----
template<int FI, int FO>
__global__ void __launch_bounds__(256) k_pool(const float* __restrict__ g,
                                              const float* __restrict__ W,
                                              const float* __restrict__ b,
                                              const float* __restrict__ ab,
                                              const int* __restrict__ batch, int N, int B,
                                              unsigned* __restrict__ pooled) {
  __shared__ float Ws[FI * FO];
  __shared__ float bs[FO];
  __shared__ float as2[2 * FO];
  __shared__ unsigned lpool[4 * FO];
  __shared__ int gid0s;
  for (int t = threadIdx.x; t < FI * FO; t += blockDim.x) Ws[t] = W[t];
  for (int t = threadIdx.x; t < FO; t += blockDim.x) bs[t] = b[t];
  for (int t = threadIdx.x; t < 2 * FO; t += blockDim.x) as2[t] = ab[t];
  if (threadIdx.x < 4 * FO) lpool[threadIdx.x] = 0u;
  int i0 = blockIdx.x * blockDim.x;
  if (threadIdx.x == 0) gid0s = batch[i0 < N ? i0 : (N - 1)];
  __syncthreads();
  int gid0 = gid0s;

  int i = i0 + threadIdx.x;
  if (i < N) {
    float gv[FI];
    const float4* g4 = (const float4*)(g + (size_t)i * FI);
    #pragma unroll
    for (int k = 0; k < FI / 4; k++) {
      float4 v = g4[k];
      gv[4 * k] = v.x; gv[4 * k + 1] = v.y; gv[4 * k + 2] = v.z; gv[4 * k + 3] = v.w;
    }
    int gid = batch[i];
    int slot = gid - gid0;
    #pragma unroll
    for (int j = 0; j < FO; j++) {
      float y = bs[j];
      #pragma unroll
      for (int k = 0; k < FI; k++) y = fmaf(gv[k], Ws[k * FO + j], y);
      float hv = fmaxf(fmaf(y, as2[j], as2[FO + j]), 0.f);
      unsigned u = __float_as_uint(hv);
      if (slot >= 0 && slot < 4) atomicMax(&lpool[slot * FO + j], u);
      else atomicMax(&pooled[(size_t)gid * FO + j], u);
    }
  }
  __syncthreads();
  for (int t = threadIdx.x; t < 4 * FO; t += blockDim.x) {
    unsigned v = lpool[t];
    int gid = gid0 + t / FO;
    if (v && gid < B) atomicMax(&pooled[(size_t)gid * FO + (t % FO)], v);
  }
}

// ---- final MLP ----
__global__ void __launch_bounds__(256) k_mlp(const unsigned* __restrict__ pooled,
                                             const float* __restrict__ W1,
                                             const float* __restrict__ b1,
                                             const float* __restrict__ W2,
                                             const float* __restrict__ b2, int B,
                                             float* __restrict__ out) {
  int gidx = blockIdx.x * blockDim.x + threadIdx.x;
  if (gidx >= B) return;
  float p[32];
  #pragma unroll
  for (int k = 0; k < 32; k++) p[k] = __uint_as_float(pooled[gidx * 32 + k]);
  float o0 = b2[0], o1 = b2[1];
  for (int j = 0; j < 64; j++) {
    float y = b1[j];
    #pragma unroll
    for (int k = 0; k < 32; k++) y = fmaf(p[k], W1[k * 64 + j], y);
    y = fmaxf(y, 0.f);
    o0 = fmaf(y, W2[j * 2 + 0], o0);
    o1 = fmaf(y, W2[j * 2 + 1], o1);
  }
  out[gidx * 2 + 0] = fmaxf(o0, 0.f);
  out[gidx * 2 + 1] = fmaxf(o1, 0.f);
}

extern "C" void kernel_launch(void* const* d_in, const int* in_sizes, int n_in,
                              void* d_out, int out_size, void* d_ws, size_t ws_size,
                              hipStream_t stream) {
  const float* x     = (const float*)d_in[0];
  const int*   ei    = (const int*)d_in[1];
  const int*   batch = (const int*)d_in[2];
  const float* bn0_g = (const float*)d_in[3];
  const float* bn0_b = (const float*)d_in[4];
  const float* W1    = (const float*)d_in[5];
  const float* b1    = (const float*)d_in[6];
  const float* bn1_g = (const float*)d_in[7];
  const float* bn1_b = (const float*)d_in[8];
  const float* W2    = (const float*)d_in[9];
  const float* b2    = (const float*)d_in[10];
  const float* bn2_g = (const float*)d_in[11];
  const float* bn2_b = (const float*)d_in[12];
  const float* W3    = (const float*)d_in[13];
  const float* b3    = (const float*)d_in[14];
  const float* bn3_g = (const float*)d_in[15];
  const float* bn3_b = (const float*)d_in[16];
  const float* L1W   = (const float*)d_in[17];
  const float* L1b   = (const float*)d_in[18];
  const float* L2W   = (const float*)d_in[19];
  const float* L2b   = (const float*)d_in[20];

  const int N = in_sizes[0];
  const int E = in_sizes[1] / 2;
  const int B = out_size / 2;
  const int* src = ei;
  const int* dst = ei + E;
  const float invN = 1.0f / (float)N;

  const int nbk = (N + BNODES - 1) >> BSH;
  const int nblk = (E + CHUNK - 1) / CHUNK;
  const int M = nbk * nblk;

  char* ws = (char*)d_ws;
  size_t off_b = 0;
  auto alloc = [&](size_t bytes) {
    char* p = ws + off_b;
    off_b += (bytes + 255) & ~(size_t)255;
    return p;
  };
  auto al = [](size_t b) { return (b + 255) & ~(size_t)255; };

  int*      offv   = (int*)alloc((size_t)N * 4);
  float*    dinv   = (float*)alloc((size_t)N * 4);
  float*    h0s    = (float*)alloc((size_t)N * 4);
  int*      bsum   = (int*)alloc(4096 * 4);
  int*      histG  = (int*)alloc((size_t)M * 4);
  int*      csr    = (int*)alloc((size_t)E * 4);

  size_t szR = al((size_t)N * 4) + al((size_t)N * 8 * 4) + al((size_t)N * 8 * 4);
  if (szR < (size_t)N * 16 * 4) szR = (size_t)N * 16 * 4;
  szR = al(szR);
  size_t szH2 = al((size_t)N * 16 * 4);
  size_t szBig = szR + szH2;
  if (szBig < (size_t)E * 4) szBig = (size_t)E * 4;
  char* bigbuf = alloc(szBig);
  u32*   pairs = (u32*)bigbuf;
  float* agg1  = (float*)bigbuf;
  float* h1    = (float*)(bigbuf + al((size_t)N * 4));
  float* agg2  = (float*)(bigbuf + al((size_t)N * 4) + al((size_t)N * 8 * 4));
  float* agg3  = (float*)bigbuf;
  float* h2    = (float*)(bigbuf + szR);

  unsigned* pooled = (unsigned*)alloc((size_t)B * 32 * 4);
  float*    stats  = (float*)alloc(1024 * 4);

  float* sums0 = stats + 0;
  float* ab0   = stats + 4;
  float* sums1 = stats + 8;
  float* ab1   = stats + 24;
  float* sums2 = stats + 40;
  float* ab2   = stats + 72;
  float* sums3 = stats + 104;
  float* ab3   = stats + 168;

  hipMemsetAsync(stats, 0, 1024 * 4, stream);
  hipMemsetAsync(pooled, 0, (size_t)B * 32 * 4, stream);

  const int T = 256;
  const int gN = (N + T - 1) / T;
  const int gS = 1024;
  const int gX = 512;
  const int nbScanM = (M + 2047) / 2048;

  k_s0<<<gS, T, 0, stream>>>(x, N, sums0);
  k_c0<<<1, 1, 0, stream>>>(sums0, bn0_g, bn0_b, invN, ab0);

  // ==== CSR build ====
  k_hist<<<nblk, T, 0, stream>>>(dst, E, nblk, nbk, histG);
  k_scan1<<<nbScanM, T, 0, stream>>>(histG, M, histG, bsum);
  k_scan2<<<1, T, 0, stream>>>(bsum, nbScanM);
  k_scan3<<<(M + T - 1) / T, T, 0, stream>>>(histG, bsum, M);
  k_binpairs<<<nblk, T, 0, stream>>>(src, dst, E, nblk, nbk, histG, pairs);
  k_bucket_csr<<<nbk, T, 0, stream>>>(pairs, histG, x, ab0, nblk, nbk, E, N,
                                      offv, dinv, h0s, csr);

  // layer 1 (FI=1 -> FO=8)
  k_gather1<<<gN, T, 0, stream>>>(offv, csr, h0s, dinv, N, E, agg1);
  k_stats8<1, 8><<<dim3(gX, 1), T, 0, stream>>>(agg1, W1, b1, N, sums1);
  k_affine<8><<<1, 64, 0, stream>>>(sums1, bn1_g, bn1_b, invN, ab1);
  k_transform<1, 8><<<gN, T, 0, stream>>>(agg1, W1, b1, ab1, dinv, N, h1);

  // layer 2 (FI=8 -> FO=16)
  k_gather<8><<<(N * 2 + T - 1) / T, T, 0, stream>>>(offv, csr, h1, dinv, N, E, agg2);
  k_stats16<8, 16><<<dim3(gX, 1), T, 0, stream>>>(agg2, W2, b2, N, sums2);
  k_affine<16><<<1, 64, 0, stream>>>(sums2, bn2_g, bn2_b, invN, ab2);
  k_transform<8, 16><<<gN, T, 0, stream>>>(agg2, W2, b2, ab2, dinv, N, h2);

  // layer 3 (FI=16 -> FO=32)
  k_gather<16><<<(N * 4 + T - 1) / T, T, 0, stream>>>(offv, csr, h2, dinv, N, E, agg3);
  k_stats16<16, 32><<<dim3(gX, 2), T, 0, stream>>>(agg3, W3, b3, N, sums3);
  k_affine<32><<<1, 64, 0, stream>>>(sums3, bn3_g, bn3_b, invN, ab3);
  k_pool<16, 32><<<gN, T, 0, stream>>>(agg3, W3, b3, ab3, batch, N, B, pooled);

  // final MLP
  k_mlp<<<(B + T - 1) / T, T, 0, stream>>>(pooled, L1W, L1b, L2W, L2b, B, (float*)d_out);
}